// Round 2
// baseline (138752.588 us; speedup 1.0000x reference)
//
#include <hip/hip_runtime.h>
#include <stdint.h>

// ---------------------------------------------------------------------------
// GRUClassifier: B=512, IS=128, T=256, H=256, L=3 (bi-dir, both dirs forward
// in time), layer attention + step attention + LN + FC.
// Strategy: bf16 MFMA (16x16x32) for all GEMMs, fp32 hidden-state carry,
// flash-style online softmax over time => no O(T) state history stored.
// Workspace budget ~47 MB (round-0 failed on ws overflow at ~446 MB).
// ---------------------------------------------------------------------------

typedef short short8 __attribute__((ext_vector_type(8)));
typedef float floatx4 __attribute__((ext_vector_type(4)));
typedef unsigned long long u64;

#define NB 512     // batch
#define NT 256     // timesteps
#define NH 256     // hidden
#define NG 768     // 3*H gate rows

__device__ __forceinline__ float bf2f(uint16_t v) {
    uint32_t u = ((uint32_t)v) << 16;
    float f;
    __builtin_memcpy(&f, &u, 4);
    return f;
}
__device__ __forceinline__ uint16_t f2bf(float f) {
    uint32_t u;
    __builtin_memcpy(&u, &f, 4);
    uint32_t r = (u + 0x7FFFu + ((u >> 16) & 1u)) >> 16;
    return (uint16_t)r;
}
__device__ __forceinline__ u64 pack4bf(float4 v) {
    u64 a = f2bf(v.x), b = f2bf(v.y), c = f2bf(v.z), d = f2bf(v.w);
    return a | (b << 16) | (c << 32) | (d << 48);
}
__device__ __forceinline__ float sigmoidf_(float x) { return 1.f / (1.f + expf(-x)); }
__device__ __forceinline__ float geluf_(float x) { return 0.5f * x * (1.f + erff(x * 0.70710678118f)); }

// ---------------- f32 -> bf16 conversion (weights) -------------------------
__global__ void k_cvt(const float* __restrict__ src, uint16_t* __restrict__ dst, int n4) {
    int i = blockIdx.x * blockDim.x + threadIdx.x;
    if (i < n4) {
        float4 v = ((const float4*)src)[i];
        ushort4 o;
        o.x = f2bf(v.x); o.y = f2bf(v.y); o.z = f2bf(v.z); o.w = f2bf(v.w);
        ((ushort4*)dst)[i] = o;
    }
}

__global__ void k_zero(float* __restrict__ p, int n4) {
    int i = blockIdx.x * blockDim.x + threadIdx.x;
    if (i < n4) ((float4*)p)[i] = make_float4(0.f, 0.f, 0.f, 0.f);
}

__global__ void k_init_md(float* __restrict__ m, float* __restrict__ d) {
    int i = blockIdx.x * blockDim.x + threadIdx.x;
    if (i < NB) { m[i] = -1e30f; d[i] = 0.f; }
}

__global__ void k_sentinel(float* __restrict__ out) {
    int i = blockIdx.x * blockDim.x + threadIdx.x;
    if (i < 1024) out[i] = -99999.0f;
}

// ---------------- encoder: encoded = mish(x @ enc_w^T + enc_b), bf16 out ----
// grid: (32768/128, 512/128) = (256,4), 256 threads (4 waves, 64x64 tiles)
__global__ __launch_bounds__(256) void k_encoder(
    const float* __restrict__ x, const float* __restrict__ enc_w,
    const float* __restrict__ enc_b, uint16_t* __restrict__ enc_out) {
    const int tid = threadIdx.x;
    const int lane = tid & 63, wid = tid >> 6;
    const int q = lane >> 4, l15 = lane & 15;
    const int wm = wid >> 1, wj = wid & 1;
    const int j0 = blockIdx.x * 128, b0 = blockIdx.y * 128;

    __shared__ uint16_t a_s[128 * 72];   // [b][64k], stride 72 (pad)
    __shared__ uint16_t w_s[128 * 72];   // [j][64k]

#pragma unroll
    for (int jj = 0; jj < 8; ++jj) {
        int u = tid + jj * 256;            // [0,2048)
        int r = u >> 4, c4 = (u & 15) * 4;
        float4 va = *(const float4*)&x[(size_t)(b0 + r) * 64 + c4];
        float4 vw = *(const float4*)&enc_w[(size_t)(j0 + r) * 64 + c4];
        *(u64*)&a_s[r * 72 + c4] = pack4bf(va);
        *(u64*)&w_s[r * 72 + c4] = pack4bf(vw);
    }
    __syncthreads();

    floatx4 acc[4][4];
#pragma unroll
    for (int mi = 0; mi < 4; ++mi)
#pragma unroll
        for (int nf = 0; nf < 4; ++nf) acc[mi][nf] = (floatx4){0.f, 0.f, 0.f, 0.f};

#pragma unroll
    for (int kc = 0; kc < 2; ++kc) {
        short8 af[4], bfg[4];
#pragma unroll
        for (int mi = 0; mi < 4; ++mi)
            af[mi] = *(const short8*)&a_s[(wm * 64 + mi * 16 + l15) * 72 + kc * 32 + q * 8];
#pragma unroll
        for (int nf = 0; nf < 4; ++nf)
            bfg[nf] = *(const short8*)&w_s[(wj * 64 + nf * 16 + l15) * 72 + kc * 32 + q * 8];
#pragma unroll
        for (int mi = 0; mi < 4; ++mi)
#pragma unroll
            for (int nf = 0; nf < 4; ++nf)
                acc[mi][nf] = __builtin_amdgcn_mfma_f32_16x16x32_bf16(af[mi], bfg[nf], acc[mi][nf], 0, 0, 0);
    }

#pragma unroll
    for (int nf = 0; nf < 4; ++nf) {
        int j = j0 + wj * 64 + nf * 16 + l15;
        float eb = enc_b[j];
#pragma unroll
        for (int mi = 0; mi < 4; ++mi)
#pragma unroll
            for (int r = 0; r < 4; ++r) {
                int b = b0 + wm * 64 + mi * 16 + q * 4 + r;
                float v = acc[mi][nf][r] + eb;
                float sp = (v > 20.f) ? v : log1pf(expf(v));
                float m = v * tanhf(sp);
                enc_out[(size_t)b * 32768 + j] = f2bf(m);
            }
    }
}

// ---------------- GRU step kernel: one (t, layer), both dirs via grid.z -----
// grid (4 e-tiles, 4 b-tiles, 2 dirs), 256 thr. Block tile: 128b x 64e x 3g.
__global__ __launch_bounds__(256) void k_step(
    int t, int l, const float* __restrict__ hR, float* __restrict__ hW,
    const uint16_t* __restrict__ enc_bf,
    const uint16_t* __restrict__ wih0_bf, const uint16_t* __restrict__ wihL_bf,
    const uint16_t* __restrict__ whh_bf,
    const float* __restrict__ bih_all, const float* __restrict__ bhh_all) {
    const int tid = threadIdx.x;
    const int lane = tid & 63, wid = tid >> 6;
    const int q = lane >> 4, l15 = lane & 15;
    const int wm = wid >> 1, wn = wid & 1;
    const int eblk = blockIdx.x * 64;
    const int b0 = blockIdx.y * 128;
    const int d = blockIdx.z;
    const int Din = (l == 0) ? 128 : 512;
    const uint16_t* wih = (l == 0) ? (wih0_bf + (size_t)d * NG * 128)
                                   : (wihL_bf + (size_t)((l - 1) * 2 + d) * NG * 512);
    const uint16_t* whh = whh_bf + (size_t)(l * 2 + d) * NG * 256;
    const float* bih = bih_all + (l * 2 + d) * NG;
    const float* bhh = bhh_all + (l * 2 + d) * NG;

    __shared__ uint16_t a_s[128 * 40];  // [b][32k] stride 40
    __shared__ uint16_t b_s[192 * 40];  // [3g*64e][32k]

    floatx4 accR[4][2], accZ[4][2], accNi[4][2], accNh[4][2];
#pragma unroll
    for (int mi = 0; mi < 4; ++mi)
#pragma unroll
        for (int ni = 0; ni < 2; ++ni) {
            floatx4 z = (floatx4){0.f, 0.f, 0.f, 0.f};
            accR[mi][ni] = z; accZ[mi][ni] = z; accNi[mi][ni] = z; accNh[mi][ni] = z;
        }

    for (int ph = 0; ph < 2; ++ph) {
        const int K = ph ? 256 : Din;
        const uint16_t* wmat = ph ? whh : wih;
        for (int kc = 0; kc < K; kc += 32) {
            __syncthreads();
            // ---- stage A (128 x 32) ----
            if (ph == 0 && l == 0) {
#pragma unroll
                for (int j = 0; j < 4; ++j) {
                    int u = tid + j * 256;
                    int r = u >> 3, c4 = (u & 7) * 4;
                    *(u64*)&a_s[r * 40 + c4] =
                        *(const u64*)&enc_bf[((size_t)(b0 + r) << 15) + t * 128 + kc + c4];
                }
            } else {
                const float* abase;
                int coff;
                if (ph == 1) {
                    abase = hR + (size_t)(2 * l + d) * NB * NH;
                    coff = kc;
                } else {
                    int s_in = 2 * (l - 1) + (kc >= 256 ? 1 : 0);
                    abase = hW + (size_t)s_in * NB * NH;
                    coff = kc & 255;
                }
#pragma unroll
                for (int j = 0; j < 4; ++j) {
                    int u = tid + j * 256;
                    int r = u >> 3, c4 = (u & 7) * 4;
                    float4 v = *(const float4*)&abase[(size_t)(b0 + r) * NH + coff + c4];
                    *(u64*)&a_s[r * 40 + c4] = pack4bf(v);
                }
            }
            // ---- stage B (192 x 32) ----
#pragma unroll
            for (int j = 0; j < 6; ++j) {
                int u = tid + j * 256;
                int r = u >> 3, c4 = (u & 7) * 4;
                int g = r >> 6, er = r & 63;
                *(u64*)&b_s[r * 40 + c4] =
                    *(const u64*)&wmat[(size_t)(g * 256 + eblk + er) * K + kc + c4];
            }
            __syncthreads();
            // ---- fragments + MFMA ----
            short8 af[4];
#pragma unroll
            for (int mi = 0; mi < 4; ++mi)
                af[mi] = *(const short8*)&a_s[(wm * 64 + mi * 16 + l15) * 40 + q * 8];
            short8 bfg[3][2];
#pragma unroll
            for (int g = 0; g < 3; ++g)
#pragma unroll
                for (int ni = 0; ni < 2; ++ni)
                    bfg[g][ni] = *(const short8*)&b_s[(g * 64 + wn * 32 + ni * 16 + l15) * 40 + q * 8];
#pragma unroll
            for (int mi = 0; mi < 4; ++mi)
#pragma unroll
                for (int ni = 0; ni < 2; ++ni) {
                    accR[mi][ni] = __builtin_amdgcn_mfma_f32_16x16x32_bf16(af[mi], bfg[0][ni], accR[mi][ni], 0, 0, 0);
                    accZ[mi][ni] = __builtin_amdgcn_mfma_f32_16x16x32_bf16(af[mi], bfg[1][ni], accZ[mi][ni], 0, 0, 0);
                    if (ph == 0)
                        accNi[mi][ni] = __builtin_amdgcn_mfma_f32_16x16x32_bf16(af[mi], bfg[2][ni], accNi[mi][ni], 0, 0, 0);
                    else
                        accNh[mi][ni] = __builtin_amdgcn_mfma_f32_16x16x32_bf16(af[mi], bfg[2][ni], accNh[mi][ni], 0, 0, 0);
                }
        }
    }

    // ---- epilogue: gates + state update ----
#pragma unroll
    for (int ni = 0; ni < 2; ++ni) {
        int e = eblk + wn * 32 + ni * 16 + l15;
        float br = bih[e], bhr = bhh[e];
        float bz = bih[256 + e], bhz = bhh[256 + e];
        float bn = bih[512 + e], bhn = bhh[512 + e];
#pragma unroll
        for (int mi = 0; mi < 4; ++mi)
#pragma unroll
            for (int r = 0; r < 4; ++r) {
                int b = b0 + wm * 64 + mi * 16 + q * 4 + r;
                float sr = accR[mi][ni][r] + br + bhr;
                float sz = accZ[mi][ni][r] + bz + bhz;
                float gi = accNi[mi][ni][r] + bn;
                float gh = accNh[mi][ni][r] + bhn;
                float rr = sigmoidf_(sr);
                float zz = sigmoidf_(sz);
                float nn = tanhf(gi + rr * gh);
                size_t hidx = ((size_t)(2 * l + d) * NB + b) * NH + e;
                float hp = hR[hidx];
                hW[hidx] = (1.f - zz) * nn + zz * hp;
            }
    }
}

// ---------------- per-step attention + online softmax ----------------------
// grid 2 blocks x 256 thr; block handles 256 batch rows.
// s[b]   = sum_l sigmoid(gelu(lh_l @ laW1^T + b1) @ laW2^T + b2)
// logit  = silu(s*(out @ saW1^T) + sb1) @ saW2^T + sb2
// online: m,d,N  with  N += exp(logit-m)*s*out
__global__ __launch_bounds__(256) void k_att(
    const float* __restrict__ hW,
    const uint16_t* __restrict__ law1_bf, const float* __restrict__ la_b1,
    const float* __restrict__ la_w2, const float* __restrict__ la_b2,
    const uint16_t* __restrict__ saw1_bf, const float* __restrict__ sa_b1,
    const float* __restrict__ sa_w2, const float* __restrict__ sa_b2,
    float* __restrict__ m_buf, float* __restrict__ d_buf,
    float* __restrict__ N_buf) {
    const int tid = threadIdx.x;
    const int lane = tid & 63, wid = tid >> 6;
    const int q = lane >> 4, l15 = lane & 15;
    const int b0 = blockIdx.x * 256;

    __shared__ uint16_t a_s[256 * 40];
    __shared__ uint16_t w_s[112 * 40];
    __shared__ float sv_s[256], lg_s[256];

    float s_acc[4][4];
#pragma unroll
    for (int mi = 0; mi < 4; ++mi)
#pragma unroll
        for (int r = 0; r < 4; ++r) s_acc[mi][r] = 0.f;

    for (int l = 0; l < 3; ++l) {
        const int nfr = (l == 2) ? 7 : 3;   // l==2 also computes sa cols (4 frags)
        const int nR = nfr * 16;
        floatx4 acc[4][7];
#pragma unroll
        for (int mi = 0; mi < 4; ++mi)
            for (int nf = 0; nf < 7; ++nf) acc[mi][nf] = (floatx4){0.f, 0.f, 0.f, 0.f};

        for (int kc = 0; kc < 512; kc += 32) {
            __syncthreads();
            // stage A: 256 rows x 32 k of concat(h[2l], h[2l+1]) in bf16
#pragma unroll
            for (int j = 0; j < 8; ++j) {
                int u = tid + j * 256;
                int r = u >> 3, c4 = (u & 7) * 4;
                int k = kc + c4;
                int s = 2 * l + (k >= 256 ? 1 : 0);
                float4 v = *(const float4*)&hW[((size_t)s * NB + (b0 + r)) * NH + (k & 255)];
                *(u64*)&a_s[r * 40 + c4] = pack4bf(v);
            }
            // stage W rows: [0,48) la_w1[l], [48,112) sa_w1 (l==2 only)
            for (int u = tid; u < nR * 8; u += 256) {
                int r = u >> 3, c4 = (u & 7) * 4;
                const uint16_t* src = (r < 48)
                    ? &law1_bf[((size_t)l * 48 + r) * 512 + kc + c4]
                    : &saw1_bf[((size_t)(r - 48)) * 512 + kc + c4];
                *(u64*)&w_s[r * 40 + c4] = *(const u64*)src;
            }
            __syncthreads();
            short8 af[4];
#pragma unroll
            for (int mi = 0; mi < 4; ++mi)
                af[mi] = *(const short8*)&a_s[(wid * 64 + mi * 16 + l15) * 40 + q * 8];
            for (int nf = 0; nf < nfr; ++nf) {
                short8 bfg = *(const short8*)&w_s[(nf * 16 + l15) * 40 + q * 8];
#pragma unroll
                for (int mi = 0; mi < 4; ++mi)
                    acc[mi][nf] = __builtin_amdgcn_mfma_f32_16x16x32_bf16(af[mi], bfg, acc[mi][nf], 0, 0, 0);
            }
        }
        // epilogue for this layer
        float b1v[3], w2v[3];
#pragma unroll
        for (int nf = 0; nf < 3; ++nf) {
            int col = nf * 16 + l15;
            b1v[nf] = la_b1[l * 48 + col];
            w2v[nf] = la_w2[l * 48 + col];
        }
        float bb2 = la_b2[l];
        float b1s[4], w2s[4], sb2 = 0.f;
        if (l == 2) {
#pragma unroll
            for (int nf = 0; nf < 4; ++nf) {
                int col = nf * 16 + l15;
                b1s[nf] = sa_b1[col];
                w2s[nf] = sa_w2[col];
            }
            sb2 = sa_b2[0];
        }
#pragma unroll
        for (int mi = 0; mi < 4; ++mi)
#pragma unroll
            for (int r = 0; r < 4; ++r) {
                float v = 0.f;
#pragma unroll
                for (int nf = 0; nf < 3; ++nf) {
                    float xx = acc[mi][nf][r] + b1v[nf];
                    v += geluf_(xx) * w2v[nf];
                }
#pragma unroll
                for (int off = 1; off < 16; off <<= 1) v += __shfl_xor(v, off, 64);
                float st = s_acc[mi][r] + sigmoidf_(v + bb2);
                s_acc[mi][r] = st;
                if (l == 2) {
                    float vs = 0.f;
#pragma unroll
                    for (int nf = 0; nf < 4; ++nf) {
                        float xx = st * acc[mi][3 + nf][r] + b1s[nf];
                        vs += xx * sigmoidf_(xx) * w2s[nf];
                    }
#pragma unroll
                    for (int off = 1; off < 16; off <<= 1) vs += __shfl_xor(vs, off, 64);
                    if (l15 == 0) {
                        int row = wid * 64 + mi * 16 + q * 4 + r;
                        sv_s[row] = st;
                        lg_s[row] = vs + sb2;
                    }
                }
            }
    }
    __syncthreads();

    // online softmax update: wave w handles rows [w*64, w*64+64)
    for (int rr = 0; rr < 64; ++rr) {
        int row = wid * 64 + rr;
        int b = b0 + row;
        float sv = sv_s[row], lg = lg_s[row];
        float m_old = m_buf[b];
        float m_new = fmaxf(m_old, lg);
        float cs = expf(m_old - m_new);
        float e = expf(lg - m_new);
        if (lane == 0) {
            m_buf[b] = m_new;
            d_buf[b] = d_buf[b] * cs + e;
        }
        float w = e * sv;
#pragma unroll
        for (int k = 0; k < 8; ++k) {
            int c = lane + k * 64;
            float outc = (c < 256)
                ? hW[(size_t)4 * NB * NH + (size_t)b * NH + c]
                : hW[(size_t)5 * NB * NH + (size_t)b * NH + (c - 256)];
            size_t ni = (size_t)b * 512 + c;
            N_buf[ni] = N_buf[ni] * cs + w * outc;
        }
    }
}

// ---------------- context = N/d, LayerNorm + FC ----------------------------
// grid 512 (one block per b), 256 thr
__global__ __launch_bounds__(256) void k_final(
    const float* __restrict__ N_buf, const float* __restrict__ d_buf,
    const float* __restrict__ ln_g, const float* __restrict__ ln_b,
    const float* __restrict__ fc_w, const float* __restrict__ fc_b,
    float* __restrict__ out) {
    const int b = blockIdx.x;
    const int t = threadIdx.x;
    __shared__ float red[256];

    float rd = 1.f / d_buf[b];
    float c0 = N_buf[(size_t)b * 512 + t] * rd;
    float c1 = N_buf[(size_t)b * 512 + 256 + t] * rd;

    // LayerNorm over 512
    red[t] = c0 + c1;
    __syncthreads();
    for (int s = 128; s > 0; s >>= 1) {
        if (t < s) red[t] += red[t + s];
        __syncthreads();
    }
    float mean = red[0] / 512.f;
    __syncthreads();
    red[t] = c0 * c0 + c1 * c1;
    __syncthreads();
    for (int s = 128; s > 0; s >>= 1) {
        if (t < s) red[t] += red[t + s];
        __syncthreads();
    }
    float var = red[0] / 512.f - mean * mean;
    __syncthreads();
    float rstd = rsqrtf(var + 1e-5f);
    float n0 = (c0 - mean) * rstd * ln_g[t] + ln_b[t];
    float n1 = (c1 - mean) * rstd * ln_g[256 + t] + ln_b[256 + t];
    float p0 = n0 * fc_w[t] + n1 * fc_w[256 + t];
    float p1 = n0 * fc_w[512 + t] + n1 * fc_w[768 + t];
    red[t] = p0;
    __syncthreads();
    for (int s = 128; s > 0; s >>= 1) {
        if (t < s) red[t] += red[t + s];
        __syncthreads();
    }
    float o0 = red[0];
    __syncthreads();
    red[t] = p1;
    __syncthreads();
    for (int s = 128; s > 0; s >>= 1) {
        if (t < s) red[t] += red[t + s];
        __syncthreads();
    }
    float o1 = red[0];
    if (t == 0) {
        out[b * 2 + 0] = o0 + fc_b[0];
        out[b * 2 + 1] = o1 + fc_b[1];
    }
}

// ---------------------------------------------------------------------------
extern "C" void kernel_launch(void* const* d_in, const int* in_sizes, int n_in,
                              void* d_out, int out_size, void* d_ws, size_t ws_size,
                              hipStream_t stream) {
    const float* x     = (const float*)d_in[0];
    const float* enc_w = (const float*)d_in[1];
    const float* enc_b = (const float*)d_in[2];
    const float* wih0  = (const float*)d_in[3];
    const float* wihL  = (const float*)d_in[4];
    const float* whh   = (const float*)d_in[5];
    const float* bih   = (const float*)d_in[6];
    const float* bhh   = (const float*)d_in[7];
    const float* la_w1 = (const float*)d_in[8];
    const float* la_b1 = (const float*)d_in[9];
    const float* la_w2 = (const float*)d_in[10];
    const float* la_b2 = (const float*)d_in[11];
    const float* sa_w1 = (const float*)d_in[12];
    const float* sa_b1 = (const float*)d_in[13];
    const float* sa_w2 = (const float*)d_in[14];
    const float* sa_b2 = (const float*)d_in[15];
    const float* ln_g  = (const float*)d_in[16];
    const float* ln_b  = (const float*)d_in[17];
    const float* fc_w  = (const float*)d_in[18];
    const float* fc_b  = (const float*)d_in[19];
    float* out = (float*)d_out;

    uint8_t* wsb = (uint8_t*)d_ws;
    size_t off = 0;
    auto alloc = [&](size_t bytes) -> void* {
        void* p = wsb + off;
        off += (bytes + 255) & ~(size_t)255;
        return p;
    };
    uint16_t* enc_bf  = (uint16_t*)alloc((size_t)NB * 32768 * 2);      // 33.55 MB
    float*    hA      = (float*)alloc((size_t)6 * NB * NH * 4);        // 3.15 MB
    float*    hB      = (float*)alloc((size_t)6 * NB * NH * 4);        // 3.15 MB
    float*    N_buf   = (float*)alloc((size_t)NB * 512 * 4);           // 1.05 MB
    float*    m_buf   = (float*)alloc((size_t)NB * 4);
    float*    d_buf   = (float*)alloc((size_t)NB * 4);
    uint16_t* wih0_bf = (uint16_t*)alloc((size_t)2 * NG * 128 * 2);    // 0.39 MB
    uint16_t* wihL_bf = (uint16_t*)alloc((size_t)2 * 2 * NG * 512 * 2);// 3.15 MB
    uint16_t* whh_bf  = (uint16_t*)alloc((size_t)3 * 2 * NG * 256 * 2);// 2.36 MB
    uint16_t* law1_bf = (uint16_t*)alloc((size_t)3 * 48 * 512 * 2);    // 0.15 MB
    uint16_t* saw1_bf = (uint16_t*)alloc((size_t)64 * 512 * 2);        // 0.07 MB
    // total ~47 MB

    if (ws_size < off) {  // workspace too small: emit recognizable sentinel
        k_sentinel<<<4, 256, 0, stream>>>(out);
        return;
    }

    auto cvt = [&](const float* s, uint16_t* dmem, int n) {
        int n4 = n / 4;
        k_cvt<<<(n4 + 255) / 256, 256, 0, stream>>>(s, dmem, n4);
    };
    cvt(wih0, wih0_bf, 196608);
    cvt(wihL, wihL_bf, 1572864);
    cvt(whh, whh_bf, 1179648);
    cvt(la_w1, law1_bf, 73728);
    cvt(sa_w1, saw1_bf, 32768);
    k_zero<<<768, 256, 0, stream>>>(hA, 196608);
    k_zero<<<256, 256, 0, stream>>>(N_buf, 65536);
    k_init_md<<<2, 256, 0, stream>>>(m_buf, d_buf);

    k_encoder<<<dim3(256, 4), 256, 0, stream>>>(x, enc_w, enc_b, enc_bf);

    float* hR = hA;
    float* hW = hB;
    for (int t = 0; t < NT; ++t) {
        for (int l = 0; l < 3; ++l)
            k_step<<<dim3(4, 4, 2), 256, 0, stream>>>(t, l, hR, hW, enc_bf, wih0_bf,
                                                      wihL_bf, whh_bf, bih, bhh);
        k_att<<<2, 256, 0, stream>>>(hW, law1_bf, la_b1, la_w2, la_b2,
                                     saw1_bf, sa_b1, sa_w2, sa_b2,
                                     m_buf, d_buf, N_buf);
        float* tmp = hR; hR = hW; hW = tmp;
    }

    k_final<<<512, 256, 0, stream>>>(N_buf, d_buf, ln_g, ln_b, fc_w, fc_b, out);
}

// Round 3
// 52108.472 us; speedup vs baseline: 2.6628x; 2.6628x over previous
//
#include <hip/hip_runtime.h>
#include <stdint.h>

// ---------------------------------------------------------------------------
// GRUClassifier persistent-scan version.
// B=512, IS=128, T=256, H=256, L=3 bi-dir (both dirs forward in time).
// One block owns 16 batch rows and runs the ENTIRE T-loop (all layers +
// attention + online softmax). No inter-block communication. 7 dispatches.
// Numerics (validated round 2): bf16 MFMA inputs, fp32 hidden carry.
// ---------------------------------------------------------------------------

typedef short short8 __attribute__((ext_vector_type(8)));
typedef float floatx4 __attribute__((ext_vector_type(4)));
typedef unsigned long long u64;

#define NB 512
#define NT 256
#define NH 256
#define NG 768
#define BLKS 32
#define BTH 512

__device__ __forceinline__ float bf2f(uint16_t v) {
    uint32_t u = ((uint32_t)v) << 16;
    float f;
    __builtin_memcpy(&f, &u, 4);
    return f;
}
__device__ __forceinline__ uint16_t f2bf(float f) {
    uint32_t u;
    __builtin_memcpy(&u, &f, 4);
    uint32_t r = (u + 0x7FFFu + ((u >> 16) & 1u)) >> 16;
    return (uint16_t)r;
}
__device__ __forceinline__ u64 pack4bf(float4 v) {
    u64 a = f2bf(v.x), b = f2bf(v.y), c = f2bf(v.z), d = f2bf(v.w);
    return a | (b << 16) | (c << 32) | (d << 48);
}
__device__ __forceinline__ float sigmoidf_(float x) { return 1.f / (1.f + expf(-x)); }
__device__ __forceinline__ float geluf_(float x) { return 0.5f * x * (1.f + erff(x * 0.70710678118f)); }

// ---------------- f32 -> bf16 conversion (weights) -------------------------
__global__ void k_cvt(const float* __restrict__ src, uint16_t* __restrict__ dst, int n4) {
    int i = blockIdx.x * blockDim.x + threadIdx.x;
    if (i < n4) {
        float4 v = ((const float4*)src)[i];
        ushort4 o;
        o.x = f2bf(v.x); o.y = f2bf(v.y); o.z = f2bf(v.z); o.w = f2bf(v.w);
        ((ushort4*)dst)[i] = o;
    }
}

__global__ void k_sentinel(float* __restrict__ out) {
    int i = blockIdx.x * blockDim.x + threadIdx.x;
    if (i < 1024) out[i] = -99999.0f;
}

// ---------------- encoder: encoded = mish(x @ enc_w^T + enc_b), bf16 out ----
// grid: (32768/128, 512/128) = (256,4), 256 threads (4 waves, 64x64 tiles)
__global__ __launch_bounds__(256) void k_encoder(
    const float* __restrict__ x, const float* __restrict__ enc_w,
    const float* __restrict__ enc_b, uint16_t* __restrict__ enc_out) {
    const int tid = threadIdx.x;
    const int lane = tid & 63, wid = tid >> 6;
    const int q = lane >> 4, l15 = lane & 15;
    const int wm = wid >> 1, wj = wid & 1;
    const int j0 = blockIdx.x * 128, b0 = blockIdx.y * 128;

    __shared__ uint16_t a_s[128 * 72];
    __shared__ uint16_t w_s[128 * 72];

#pragma unroll
    for (int jj = 0; jj < 8; ++jj) {
        int u = tid + jj * 256;
        int r = u >> 4, c4 = (u & 15) * 4;
        float4 va = *(const float4*)&x[(size_t)(b0 + r) * 64 + c4];
        float4 vw = *(const float4*)&enc_w[(size_t)(j0 + r) * 64 + c4];
        *(u64*)&a_s[r * 72 + c4] = pack4bf(va);
        *(u64*)&w_s[r * 72 + c4] = pack4bf(vw);
    }
    __syncthreads();

    floatx4 acc[4][4];
#pragma unroll
    for (int mi = 0; mi < 4; ++mi)
#pragma unroll
        for (int nf = 0; nf < 4; ++nf) acc[mi][nf] = (floatx4){0.f, 0.f, 0.f, 0.f};

#pragma unroll
    for (int kc = 0; kc < 2; ++kc) {
        short8 af[4], bfg[4];
#pragma unroll
        for (int mi = 0; mi < 4; ++mi)
            af[mi] = *(const short8*)&a_s[(wm * 64 + mi * 16 + l15) * 72 + kc * 32 + q * 8];
#pragma unroll
        for (int nf = 0; nf < 4; ++nf)
            bfg[nf] = *(const short8*)&w_s[(wj * 64 + nf * 16 + l15) * 72 + kc * 32 + q * 8];
#pragma unroll
        for (int mi = 0; mi < 4; ++mi)
#pragma unroll
            for (int nf = 0; nf < 4; ++nf)
                acc[mi][nf] = __builtin_amdgcn_mfma_f32_16x16x32_bf16(af[mi], bfg[nf], acc[mi][nf], 0, 0, 0);
    }

#pragma unroll
    for (int nf = 0; nf < 4; ++nf) {
        int j = j0 + wj * 64 + nf * 16 + l15;
        float eb = enc_b[j];
#pragma unroll
        for (int mi = 0; mi < 4; ++mi)
#pragma unroll
            for (int r = 0; r < 4; ++r) {
                int b = b0 + wm * 64 + mi * 16 + q * 4 + r;
                float v = acc[mi][nf][r] + eb;
                float sp = (v > 20.f) ? v : log1pf(expf(v));
                float m = v * tanhf(sp);
                enc_out[(size_t)b * 32768 + j] = f2bf(m);
            }
    }
}

// ---------------- persistent scan kernel -----------------------------------
// grid 32 blocks x 512 thr (8 waves). Block owns batch rows [b0, b0+16).
// Wave w: dir d=w>>2, h-col slice ew=(w&3)*64 (4 tiles of 16).
// h fp32 carry in registers; bf16 shadow in LDS for MFMA A-operands.
// Weights: direct global->VGPR B-fragments (L2/L3 resident).
__global__ __launch_bounds__(BTH, 2) void k_scan(
    const uint16_t* __restrict__ enc_bf,
    const uint16_t* __restrict__ wih0_bf, const uint16_t* __restrict__ wihL_bf,
    const uint16_t* __restrict__ whh_bf,
    const float* __restrict__ bih, const float* __restrict__ bhh,
    const uint16_t* __restrict__ law1_bf, const float* __restrict__ la_b1,
    const float* __restrict__ la_w2, const float* __restrict__ la_b2,
    const uint16_t* __restrict__ saw1_bf, const float* __restrict__ sa_b1,
    const float* __restrict__ sa_w2, const float* __restrict__ sa_b2,
    const float* __restrict__ ln_g, const float* __restrict__ ln_b,
    const float* __restrict__ fc_w, const float* __restrict__ fc_b,
    float* __restrict__ out) {
    const int tid = threadIdx.x;
    const int w = tid >> 6;
    const int lane = tid & 63;
    const int q = lane >> 4, l15 = lane & 15;
    const int d = w >> 2;
    const int ew = (w & 3) * 64;
    const int b0 = blockIdx.x * 16;

    __shared__ uint16_t hbf[6 * 16 * 264];   // [state][row][col], pad 264
    __shared__ float laP[3][3][16];          // la per-(l,nf) row partials
    __shared__ float saT[4][16][17];         // raw sa pre-acts
    __shared__ float s_s[16], lg_s[16];

    for (int i = tid; i < 6 * 16 * 264; i += BTH) hbf[i] = 0;

    float hreg[3][4][4];                     // fp32 carry: [layer][tile][row]
#pragma unroll
    for (int l = 0; l < 3; ++l)
#pragma unroll
        for (int ht = 0; ht < 4; ++ht)
#pragma unroll
            for (int r = 0; r < 4; ++r) hreg[l][ht][r] = 0.f;

    float nacc[16];                          // online-softmax numerator
#pragma unroll
    for (int j = 0; j < 16; ++j) nacc[j] = 0.f;
    float m_r = -1e30f, d_r = 0.f;

    // bias preload: r,z pre-summed (bih+bhh); n-gate biases loaded in epilogue
    float bRv[3][4], bZv[3][4];
#pragma unroll
    for (int l = 0; l < 3; ++l) {
        int base = (l * 2 + d) * NG;
#pragma unroll
        for (int ht = 0; ht < 4; ++ht) {
            int e = ew + ht * 16 + l15;
            bRv[l][ht] = bih[base + e] + bhh[base + e];
            bZv[l][ht] = bih[base + 256 + e] + bhh[base + 256 + e];
        }
    }
    // attention job-A constants (all waves run one la job)
    const int lA = w / 3, nfA = w % 3;       // jobs (0,0)..(2,1)
    const float b1A = la_b1[lA * 48 + nfA * 16 + l15];
    const float w2A = la_w2[lA * 48 + nfA * 16 + l15];
    float b1B = 0.f, w2B = 0.f;
    if (w == 0) { b1B = la_b1[2 * 48 + 2 * 16 + l15]; w2B = la_w2[2 * 48 + 2 * 16 + l15]; }

    __syncthreads();

    for (int t = 0; t < NT; ++t) {
#pragma unroll
        for (int l = 0; l < 3; ++l) {
            floatx4 aR[4], aZ[4], aNi[4], aNh[4];
#pragma unroll
            for (int ht = 0; ht < 4; ++ht) {
                floatx4 z = (floatx4){0.f, 0.f, 0.f, 0.f};
                aR[ht] = z; aZ[ht] = z; aNi[ht] = z; aNh[ht] = z;
            }
            // ---- gi phase ----
            if (l == 0) {
                const uint16_t* xb = enc_bf + ((size_t)(b0 + l15) << 15) + t * 128 + q * 8;
                const uint16_t* wih = wih0_bf + (size_t)d * NG * 128;
#pragma unroll
                for (int kc = 0; kc < 128; kc += 32) {
                    short8 afr = *(const short8*)(xb + kc);
#pragma unroll
                    for (int ht = 0; ht < 4; ++ht) {
                        const uint16_t* wr = wih + (size_t)(ew + ht * 16 + l15) * 128 + kc + q * 8;
                        aR[ht]  = __builtin_amdgcn_mfma_f32_16x16x32_bf16(afr, *(const short8*)wr, aR[ht], 0, 0, 0);
                        aZ[ht]  = __builtin_amdgcn_mfma_f32_16x16x32_bf16(afr, *(const short8*)(wr + 256 * 128), aZ[ht], 0, 0, 0);
                        aNi[ht] = __builtin_amdgcn_mfma_f32_16x16x32_bf16(afr, *(const short8*)(wr + 512 * 128), aNi[ht], 0, 0, 0);
                    }
                }
            } else {
                const uint16_t* wih = wihL_bf + (size_t)((l - 1) * 2 + d) * NG * 512;
#pragma unroll 2
                for (int kc = 0; kc < 512; kc += 32) {
                    int k = kc + q * 8;
                    int s = 2 * (l - 1) + (k >= 256 ? 1 : 0);
                    short8 afr = *(const short8*)&hbf[(size_t)(s * 16 + l15) * 264 + (k & 255)];
#pragma unroll
                    for (int ht = 0; ht < 4; ++ht) {
                        const uint16_t* wr = wih + (size_t)(ew + ht * 16 + l15) * 512 + kc + q * 8;
                        aR[ht]  = __builtin_amdgcn_mfma_f32_16x16x32_bf16(afr, *(const short8*)wr, aR[ht], 0, 0, 0);
                        aZ[ht]  = __builtin_amdgcn_mfma_f32_16x16x32_bf16(afr, *(const short8*)(wr + 256 * 512), aZ[ht], 0, 0, 0);
                        aNi[ht] = __builtin_amdgcn_mfma_f32_16x16x32_bf16(afr, *(const short8*)(wr + 512 * 512), aNi[ht], 0, 0, 0);
                    }
                }
            }
            // ---- gh phase ----
            {
                const uint16_t* whhp = whh_bf + (size_t)(l * 2 + d) * NG * 256;
#pragma unroll 2
                for (int kc = 0; kc < 256; kc += 32) {
                    short8 afr = *(const short8*)&hbf[(size_t)((2 * l + d) * 16 + l15) * 264 + kc + q * 8];
#pragma unroll
                    for (int ht = 0; ht < 4; ++ht) {
                        const uint16_t* wr = whhp + (size_t)(ew + ht * 16 + l15) * 256 + kc + q * 8;
                        aR[ht]  = __builtin_amdgcn_mfma_f32_16x16x32_bf16(afr, *(const short8*)wr, aR[ht], 0, 0, 0);
                        aZ[ht]  = __builtin_amdgcn_mfma_f32_16x16x32_bf16(afr, *(const short8*)(wr + 256 * 256), aZ[ht], 0, 0, 0);
                        aNh[ht] = __builtin_amdgcn_mfma_f32_16x16x32_bf16(afr, *(const short8*)(wr + 512 * 256), aNh[ht], 0, 0, 0);
                    }
                }
            }
            __syncthreads();   // all waves done reading hbf before overwrite
            // ---- epilogue: gates + state update ----
            {
                int base = (l * 2 + d) * NG;
#pragma unroll
                for (int ht = 0; ht < 4; ++ht) {
                    int e = ew + ht * 16 + l15;
                    float bn = bih[base + 512 + e];
                    float bhn = bhh[base + 512 + e];
                    float bR = bRv[l][ht], bZ = bZv[l][ht];
#pragma unroll
                    for (int r = 0; r < 4; ++r) {
                        float rr = sigmoidf_(aR[ht][r] + bR);
                        float zz = sigmoidf_(aZ[ht][r] + bZ);
                        float nn = tanhf(aNi[ht][r] + bn + rr * (aNh[ht][r] + bhn));
                        float hn = (1.f - zz) * nn + zz * hreg[l][ht][r];
                        hreg[l][ht][r] = hn;
                        hbf[(size_t)((2 * l + d) * 16 + q * 4 + r) * 264 + e] = f2bf(hn);
                    }
                }
            }
            __syncthreads();   // writes visible to all waves
        }

        // ---------------- per-step attention ----------------
        // job A: la(lA, nfA)
        {
            floatx4 ac = (floatx4){0.f, 0.f, 0.f, 0.f};
#pragma unroll 2
            for (int kc = 0; kc < 512; kc += 32) {
                int k = kc + q * 8;
                int s = 2 * lA + (k >= 256 ? 1 : 0);
                short8 afr = *(const short8*)&hbf[(size_t)(s * 16 + l15) * 264 + (k & 255)];
                const uint16_t* wr = law1_bf + (size_t)(lA * 48 + nfA * 16 + l15) * 512 + k;
                ac = __builtin_amdgcn_mfma_f32_16x16x32_bf16(afr, *(const short8*)wr, ac, 0, 0, 0);
            }
#pragma unroll
            for (int r = 0; r < 4; ++r) {
                float v = geluf_(ac[r] + b1A) * w2A;
                v += __shfl_xor(v, 1, 64);
                v += __shfl_xor(v, 2, 64);
                v += __shfl_xor(v, 4, 64);
                v += __shfl_xor(v, 8, 64);
                if (l15 == 0) laP[lA][nfA][q * 4 + r] = v;
            }
        }
        // job B
        if (w == 0) {          // la(2,2)
            floatx4 ac = (floatx4){0.f, 0.f, 0.f, 0.f};
#pragma unroll 2
            for (int kc = 0; kc < 512; kc += 32) {
                int k = kc + q * 8;
                int s = 4 + (k >= 256 ? 1 : 0);
                short8 afr = *(const short8*)&hbf[(size_t)(s * 16 + l15) * 264 + (k & 255)];
                const uint16_t* wr = law1_bf + (size_t)(2 * 48 + 2 * 16 + l15) * 512 + k;
                ac = __builtin_amdgcn_mfma_f32_16x16x32_bf16(afr, *(const short8*)wr, ac, 0, 0, 0);
            }
#pragma unroll
            for (int r = 0; r < 4; ++r) {
                float v = geluf_(ac[r] + b1B) * w2B;
                v += __shfl_xor(v, 1, 64);
                v += __shfl_xor(v, 2, 64);
                v += __shfl_xor(v, 4, 64);
                v += __shfl_xor(v, 8, 64);
                if (l15 == 0) laP[2][2][q * 4 + r] = v;
            }
        } else if (w <= 4) {   // sa tile nf = w-1, raw pre-acts
            int nf = w - 1;
            floatx4 ac = (floatx4){0.f, 0.f, 0.f, 0.f};
#pragma unroll 2
            for (int kc = 0; kc < 512; kc += 32) {
                int k = kc + q * 8;
                int s = 4 + (k >= 256 ? 1 : 0);
                short8 afr = *(const short8*)&hbf[(size_t)(s * 16 + l15) * 264 + (k & 255)];
                const uint16_t* wr = saw1_bf + (size_t)(nf * 16 + l15) * 512 + k;
                ac = __builtin_amdgcn_mfma_f32_16x16x32_bf16(afr, *(const short8*)wr, ac, 0, 0, 0);
            }
#pragma unroll
            for (int r = 0; r < 4; ++r) saT[nf][q * 4 + r][l15] = ac[r];
        }
        __syncthreads();
        // s and logits (wave 0: lanes row=l15, tile=q)
        if (w == 0) {
            int row = l15;
            float sv = 0.f;
#pragma unroll
            for (int l = 0; l < 3; ++l)
                sv += sigmoidf_(laP[l][0][row] + laP[l][1][row] + laP[l][2][row] + la_b2[l]);
            float a2 = 0.f;
#pragma unroll
            for (int i = 0; i < 16; ++i) {
                int c = q * 16 + i;
                float pre = sv * saT[q][row][i] + sa_b1[c];
                a2 += pre * sigmoidf_(pre) * sa_w2[c];
            }
            a2 += __shfl_xor(a2, 16, 64);
            a2 += __shfl_xor(a2, 32, 64);
            if (q == 0 && lane < 16) { s_s[row] = sv; lg_s[row] = a2 + sa_b2[0]; }
        }
        __syncthreads();
        // online softmax update (wave w owns rows 2w, 2w+1)
        {
            int myrow = 2 * w + (lane >> 5);
            int ci = lane & 31;
            float lg = lg_s[myrow], sv = s_s[myrow];
            float mn = fmaxf(m_r, lg);
            float cs = expf(m_r - mn);
            float e = expf(lg - mn);
            m_r = mn;
            d_r = d_r * cs + e;
            float wf = e * sv;
            int st = 4 + (ci >> 4);
            int c0 = (ci & 15) * 16;
            const uint16_t* hp = &hbf[(size_t)(st * 16 + myrow) * 264 + c0];
            short8 o0 = *(const short8*)hp;
            short8 o1 = *(const short8*)(hp + 8);
#pragma unroll
            for (int j = 0; j < 8; ++j) {
                nacc[j]     = nacc[j] * cs + wf * bf2f((uint16_t)o0[j]);
                nacc[8 + j] = nacc[8 + j] * cs + wf * bf2f((uint16_t)o1[j]);
            }
        }
    }

    // ---------------- finalize: context -> LN -> FC ----------------
    {
        int myrow = 2 * w + (lane >> 5);
        int ci = lane & 31;
        float dinv = 1.f / d_r;
        float cv[16];
        float s1 = 0.f, s2 = 0.f;
#pragma unroll
        for (int j = 0; j < 16; ++j) {
            cv[j] = nacc[j] * dinv;
            s1 += cv[j];
            s2 += cv[j] * cv[j];
        }
        s1 += __shfl_xor(s1, 1, 64);  s2 += __shfl_xor(s2, 1, 64);
        s1 += __shfl_xor(s1, 2, 64);  s2 += __shfl_xor(s2, 2, 64);
        s1 += __shfl_xor(s1, 4, 64);  s2 += __shfl_xor(s2, 4, 64);
        s1 += __shfl_xor(s1, 8, 64);  s2 += __shfl_xor(s2, 8, 64);
        s1 += __shfl_xor(s1, 16, 64); s2 += __shfl_xor(s2, 16, 64);
        float mean = s1 / 512.f;
        float var = s2 / 512.f - mean * mean;
        float rstd = rsqrtf(var + 1e-5f);
        float p0 = 0.f, p1 = 0.f;
#pragma unroll
        for (int j = 0; j < 16; ++j) {
            int g = ci * 16 + j;
            float nv = (cv[j] - mean) * rstd * ln_g[g] + ln_b[g];
            p0 += nv * fc_w[g];
            p1 += nv * fc_w[512 + g];
        }
        p0 += __shfl_xor(p0, 1, 64);  p1 += __shfl_xor(p1, 1, 64);
        p0 += __shfl_xor(p0, 2, 64);  p1 += __shfl_xor(p1, 2, 64);
        p0 += __shfl_xor(p0, 4, 64);  p1 += __shfl_xor(p1, 4, 64);
        p0 += __shfl_xor(p0, 8, 64);  p1 += __shfl_xor(p1, 8, 64);
        p0 += __shfl_xor(p0, 16, 64); p1 += __shfl_xor(p1, 16, 64);
        if ((lane & 31) == 0) {
            out[(b0 + myrow) * 2 + 0] = p0 + fc_b[0];
            out[(b0 + myrow) * 2 + 1] = p1 + fc_b[1];
        }
    }
}

// ---------------------------------------------------------------------------
extern "C" void kernel_launch(void* const* d_in, const int* in_sizes, int n_in,
                              void* d_out, int out_size, void* d_ws, size_t ws_size,
                              hipStream_t stream) {
    const float* x     = (const float*)d_in[0];
    const float* enc_w = (const float*)d_in[1];
    const float* enc_b = (const float*)d_in[2];
    const float* wih0  = (const float*)d_in[3];
    const float* wihL  = (const float*)d_in[4];
    const float* whh   = (const float*)d_in[5];
    const float* bih   = (const float*)d_in[6];
    const float* bhh   = (const float*)d_in[7];
    const float* la_w1 = (const float*)d_in[8];
    const float* la_b1 = (const float*)d_in[9];
    const float* la_w2 = (const float*)d_in[10];
    const float* la_b2 = (const float*)d_in[11];
    const float* sa_w1 = (const float*)d_in[12];
    const float* sa_b1 = (const float*)d_in[13];
    const float* sa_w2 = (const float*)d_in[14];
    const float* sa_b2 = (const float*)d_in[15];
    const float* ln_g  = (const float*)d_in[16];
    const float* ln_b  = (const float*)d_in[17];
    const float* fc_w  = (const float*)d_in[18];
    const float* fc_b  = (const float*)d_in[19];
    float* out = (float*)d_out;

    uint8_t* wsb = (uint8_t*)d_ws;
    size_t off = 0;
    auto alloc = [&](size_t bytes) -> void* {
        void* p = wsb + off;
        off += (bytes + 255) & ~(size_t)255;
        return p;
    };
    uint16_t* enc_bf  = (uint16_t*)alloc((size_t)NB * 32768 * 2);        // 33.55 MB
    uint16_t* wih0_bf = (uint16_t*)alloc((size_t)2 * NG * 128 * 2);      // 0.39 MB
    uint16_t* wihL_bf = (uint16_t*)alloc((size_t)2 * 2 * NG * 512 * 2);  // 3.15 MB
    uint16_t* whh_bf  = (uint16_t*)alloc((size_t)3 * 2 * NG * 256 * 2);  // 2.36 MB
    uint16_t* law1_bf = (uint16_t*)alloc((size_t)3 * 48 * 512 * 2);      // 0.15 MB
    uint16_t* saw1_bf = (uint16_t*)alloc((size_t)64 * 512 * 2);          // 0.07 MB
    // total ~39.7 MB

    if (ws_size < off) {
        k_sentinel<<<4, 256, 0, stream>>>(out);
        return;
    }

    auto cvt = [&](const float* s, uint16_t* dmem, int n) {
        int n4 = n / 4;
        k_cvt<<<(n4 + 255) / 256, 256, 0, stream>>>(s, dmem, n4);
    };
    cvt(wih0, wih0_bf, 196608);
    cvt(wihL, wihL_bf, 1572864);
    cvt(whh, whh_bf, 1179648);
    cvt(la_w1, law1_bf, 73728);
    cvt(sa_w1, saw1_bf, 32768);

    k_encoder<<<dim3(256, 4), 256, 0, stream>>>(x, enc_w, enc_b, enc_bf);

    k_scan<<<BLKS, BTH, 0, stream>>>(enc_bf, wih0_bf, wihL_bf, whh_bf,
                                     bih, bhh, law1_bf, la_b1, la_w2, la_b2,
                                     saw1_bf, sa_b1, sa_w2, sa_b2,
                                     ln_g, ln_b, fc_w, fc_b, out);
}

// Round 4
// 10499.120 us; speedup vs baseline: 13.2156x; 4.9631x over previous
//
#include <hip/hip_runtime.h>
#include <stdint.h>

// ---------------------------------------------------------------------------
// GRUClassifier stage-pipelined version.
// B=512, IS=128, T=256, H=256, L=3 bi-dir (both dirs forward in time).
// 7 pipeline stages ((l,d) x 6 GRU + attention) x 32 batch tiles = 224 blocks.
// role = blockIdx%8 pins each stage to one XCD => stage weights fit its 4MB L2.
// Handoff: global bf16 ring (R=8) + device-scope flags. Producer: ordinary
// stores + agent-RELEASE flag (L2 writeback, no invalidate). Consumer:
// RELAXED flag spin + sc0/sc1 coherent loads (cache bypass) -- L2 weight
// residency is never invalidated. Back-pressure via consumed counters.
// Numerics (validated round 2): bf16 MFMA inputs, fp32 hidden carry.
// ---------------------------------------------------------------------------

typedef short short8 __attribute__((ext_vector_type(8)));
typedef float floatx4 __attribute__((ext_vector_type(4)));
typedef unsigned long long u64;

#define NB 512
#define NT 256
#define NH 256
#define NG 768
#define R_RING 8
#define BTH 512

__device__ __forceinline__ float bf2f(uint16_t v) {
    uint32_t u = ((uint32_t)v) << 16;
    float f;
    __builtin_memcpy(&f, &u, 4);
    return f;
}
__device__ __forceinline__ uint16_t f2bf(float f) {
    uint32_t u;
    __builtin_memcpy(&u, &f, 4);
    uint32_t r = (u + 0x7FFFu + ((u >> 16) & 1u)) >> 16;
    return (uint16_t)r;
}
__device__ __forceinline__ u64 pack4bf(float4 v) {
    u64 a = f2bf(v.x), b = f2bf(v.y), c = f2bf(v.z), d = f2bf(v.w);
    return a | (b << 16) | (c << 32) | (d << 48);
}
__device__ __forceinline__ float sigmoidf_(float x) { return 1.f / (1.f + expf(-x)); }
__device__ __forceinline__ float geluf_(float x) { return 0.5f * x * (1.f + erff(x * 0.70710678118f)); }

// coherent 16B load: bypasses L1/L2 (reads at coherence point). waitcnt folded
// in so the result register is valid on exit (no compiler-copy hazard).
__device__ __forceinline__ int4 ld_coh16(const void* p) {
    int4 v;
    asm volatile("global_load_dwordx4 %0, %1, off sc0 sc1\n\ts_waitcnt vmcnt(0)"
                 : "=v"(v) : "v"(p) : "memory");
    return v;
}

#define PIDX(s, t, b) ((((s) * NT) + (t)) * 32 + (b))

// ---------------- small utility kernels ------------------------------------
__global__ void k_cvt(const float* __restrict__ src, uint16_t* __restrict__ dst, int n4) {
    int i = blockIdx.x * blockDim.x + threadIdx.x;
    if (i < n4) {
        float4 v = ((const float4*)src)[i];
        ushort4 o;
        o.x = f2bf(v.x); o.y = f2bf(v.y); o.z = f2bf(v.z); o.w = f2bf(v.w);
        ((ushort4*)dst)[i] = o;
    }
}

__global__ void k_zero(float* __restrict__ p, int n4) {
    int i = blockIdx.x * blockDim.x + threadIdx.x;
    if (i < n4) ((float4*)p)[i] = make_float4(0.f, 0.f, 0.f, 0.f);
}

__global__ void k_sentinel(float* __restrict__ out) {
    int i = blockIdx.x * blockDim.x + threadIdx.x;
    if (i < 1024) out[i] = -99999.0f;
}

// ---------------- encoder: encoded = mish(x @ enc_w^T + enc_b), bf16 out ----
__global__ __launch_bounds__(256) void k_encoder(
    const float* __restrict__ x, const float* __restrict__ enc_w,
    const float* __restrict__ enc_b, uint16_t* __restrict__ enc_out) {
    const int tid = threadIdx.x;
    const int lane = tid & 63, wid = tid >> 6;
    const int q = lane >> 4, l15 = lane & 15;
    const int wm = wid >> 1, wj = wid & 1;
    const int j0 = blockIdx.x * 128, b0 = blockIdx.y * 128;

    __shared__ uint16_t a_s[128 * 72];
    __shared__ uint16_t w_s[128 * 72];

#pragma unroll
    for (int jj = 0; jj < 8; ++jj) {
        int u = tid + jj * 256;
        int r = u >> 4, c4 = (u & 15) * 4;
        float4 va = *(const float4*)&x[(size_t)(b0 + r) * 64 + c4];
        float4 vw = *(const float4*)&enc_w[(size_t)(j0 + r) * 64 + c4];
        *(u64*)&a_s[r * 72 + c4] = pack4bf(va);
        *(u64*)&w_s[r * 72 + c4] = pack4bf(vw);
    }
    __syncthreads();

    floatx4 acc[4][4];
#pragma unroll
    for (int mi = 0; mi < 4; ++mi)
#pragma unroll
        for (int nf = 0; nf < 4; ++nf) acc[mi][nf] = (floatx4){0.f, 0.f, 0.f, 0.f};

#pragma unroll
    for (int kc = 0; kc < 2; ++kc) {
        short8 af[4], bfg[4];
#pragma unroll
        for (int mi = 0; mi < 4; ++mi)
            af[mi] = *(const short8*)&a_s[(wm * 64 + mi * 16 + l15) * 72 + kc * 32 + q * 8];
#pragma unroll
        for (int nf = 0; nf < 4; ++nf)
            bfg[nf] = *(const short8*)&w_s[(wj * 64 + nf * 16 + l15) * 72 + kc * 32 + q * 8];
#pragma unroll
        for (int mi = 0; mi < 4; ++mi)
#pragma unroll
            for (int nf = 0; nf < 4; ++nf)
                acc[mi][nf] = __builtin_amdgcn_mfma_f32_16x16x32_bf16(af[mi], bfg[nf], acc[mi][nf], 0, 0, 0);
    }

#pragma unroll
    for (int nf = 0; nf < 4; ++nf) {
        int j = j0 + wj * 64 + nf * 16 + l15;
        float eb = enc_b[j];
#pragma unroll
        for (int mi = 0; mi < 4; ++mi)
#pragma unroll
            for (int r = 0; r < 4; ++r) {
                int b = b0 + wm * 64 + mi * 16 + q * 4 + r;
                float v = acc[mi][nf][r] + eb;
                float sp = (v > 20.f) ? v : log1pf(expf(v));
                float m = v * tanhf(sp);
                enc_out[(size_t)b * 32768 + j] = f2bf(m);
            }
    }
}

// ---------------- shared memory layouts ------------------------------------
struct SGru {
    uint16_t x_s[16 * 520];   // gi input, [row][col]
    uint16_t h_s[16 * 264];   // own h(t-1) bf16 shadow
};
struct SAtt {
    uint16_t hbf[6 * 16 * 264];
    float laP[3][3][16];
    float saT[4][16][17];
    float s_s[16], lg_s[16];
};
union SMem { SGru g; SAtt a; };

// ---------------- stage-pipelined scan kernel ------------------------------
// grid 256 x 512 thr. role = blockIdx%8 (0..5 GRU (l,d), 6 attn, 7 idle).
// btile = blockIdx/8 owns batch rows [btile*16, btile*16+16).
__global__ __launch_bounds__(BTH) void k_scan(
    const uint16_t* __restrict__ enc_bf,
    const uint16_t* __restrict__ wih0_bf, const uint16_t* __restrict__ wihL_bf,
    const uint16_t* __restrict__ whh_bf,
    const float* __restrict__ bih, const float* __restrict__ bhh,
    const uint16_t* __restrict__ law1_bf, const float* __restrict__ la_b1,
    const float* __restrict__ la_w2, const float* __restrict__ la_b2,
    const uint16_t* __restrict__ saw1_bf, const float* __restrict__ sa_b1,
    const float* __restrict__ sa_w2, const float* __restrict__ sa_b2,
    const float* __restrict__ ln_g, const float* __restrict__ ln_b,
    const float* __restrict__ fc_w, const float* __restrict__ fc_b,
    uint16_t* __restrict__ ring, int* produced, int* consumed,
    float* __restrict__ out) {
    const int role = blockIdx.x & 7;
    const int btile = blockIdx.x >> 3;
    if (role == 7) return;
    const int tid = threadIdx.x;
    const int w = tid >> 6;
    const int lane = tid & 63;
    const int q = lane >> 4, l15 = lane & 15;
    const int b0 = btile * 16;

    __shared__ SMem sm;

    if (role < 6) {
        // =================== GRU stage (l, d) ==============================
        const int l = role >> 1, dd = role & 1;
        const int Kin = (l == 0) ? 128 : 512;
        const uint16_t* wih = (l == 0) ? wih0_bf + (size_t)dd * NG * 128
                                       : wihL_bf + (size_t)((l - 1) * 2 + dd) * NG * 512;
        const uint16_t* whh = whh_bf + (size_t)role * NG * 256;
        const int ew = w * 32;                   // wave e-slice (2 N-tiles)
        const int ncons_my = (l == 2) ? 1 : 3;

        for (int i = tid; i < 16 * 264; i += BTH) sm.g.h_s[i] = 0;

        float bR[2], bZ[2], bN[2], bHN[2];
        {
            int base = role * NG;
#pragma unroll
            for (int nt = 0; nt < 2; ++nt) {
                int e = ew + nt * 16 + l15;
                bR[nt] = bih[base + e] + bhh[base + e];
                bZ[nt] = bih[base + 256 + e] + bhh[base + 256 + e];
                bN[nt] = bih[base + 512 + e];
                bHN[nt] = bhh[base + 512 + e];
            }
        }
        float hreg[2][4];
#pragma unroll
        for (int nt = 0; nt < 2; ++nt)
#pragma unroll
            for (int r = 0; r < 4; ++r) hreg[nt][r] = 0.f;
        __syncthreads();

        for (int t = 0; t < NT; ++t) {
            // ---- waits: back-pressure + upstream flags (thread 0) ----
            if (tid == 0) {
                if (t >= R_RING) {
                    const int* cp = &consumed[PIDX(role, t - R_RING, btile)];
                    while (__hip_atomic_load(cp, __ATOMIC_RELAXED, __HIP_MEMORY_SCOPE_AGENT) < ncons_my)
                        __builtin_amdgcn_s_sleep(1);
                }
                if (l > 0) {
                    const int* p0 = &produced[PIDX(2 * (l - 1), t, btile)];
                    const int* p1 = &produced[PIDX(2 * (l - 1) + 1, t, btile)];
                    while (__hip_atomic_load(p0, __ATOMIC_RELAXED, __HIP_MEMORY_SCOPE_AGENT) == 0)
                        __builtin_amdgcn_s_sleep(1);
                    while (__hip_atomic_load(p1, __ATOMIC_RELAXED, __HIP_MEMORY_SCOPE_AGENT) == 0)
                        __builtin_amdgcn_s_sleep(1);
                }
            }
            __syncthreads();
            // ---- stage gi input into x_s ----
            if (l == 0) {
                if (tid < 256) {
                    int r = tid >> 4, c0 = (tid & 15) * 8;
                    *(int4*)&sm.g.x_s[r * 520 + c0] =
                        *(const int4*)&enc_bf[((size_t)(b0 + r) << 15) + t * 128 + c0];
                }
            } else {
#pragma unroll
                for (int j = 0; j < 2; ++j) {
                    int u = tid + j * 512;
                    int r = u >> 6, c0 = (u & 63) * 8;
                    int s = 2 * (l - 1) + (c0 >= 256 ? 1 : 0);
                    const uint16_t* src =
                        ring + ((size_t)((t & 7) * 6 + s) * NB + (b0 + r)) * NH + (c0 & 255);
                    int4 v = ld_coh16(src);
                    *(int4*)&sm.g.x_s[r * 520 + c0] = v;
                }
            }
            __syncthreads();
            if (l > 0 && tid == 0) {
                __hip_atomic_fetch_add(&consumed[PIDX(2 * (l - 1), t, btile)], 1,
                                       __ATOMIC_RELAXED, __HIP_MEMORY_SCOPE_AGENT);
                __hip_atomic_fetch_add(&consumed[PIDX(2 * (l - 1) + 1, t, btile)], 1,
                                       __ATOMIC_RELAXED, __HIP_MEMORY_SCOPE_AGENT);
            }
            // ---- compute: gi + gh ----
            floatx4 aR[2], aZ[2], aNi[2], aNh[2];
#pragma unroll
            for (int nt = 0; nt < 2; ++nt) {
                floatx4 z = (floatx4){0.f, 0.f, 0.f, 0.f};
                aR[nt] = z; aZ[nt] = z; aNi[nt] = z; aNh[nt] = z;
            }
            if (l == 0) {
#pragma unroll 2
                for (int kc = 0; kc < 128; kc += 32) {
                    short8 afr = *(const short8*)&sm.g.x_s[l15 * 520 + kc + q * 8];
#pragma unroll
                    for (int nt = 0; nt < 2; ++nt) {
                        const uint16_t* wr = wih + (size_t)(ew + nt * 16 + l15) * 128 + kc + q * 8;
                        aR[nt]  = __builtin_amdgcn_mfma_f32_16x16x32_bf16(afr, *(const short8*)wr, aR[nt], 0, 0, 0);
                        aZ[nt]  = __builtin_amdgcn_mfma_f32_16x16x32_bf16(afr, *(const short8*)(wr + 256 * 128), aZ[nt], 0, 0, 0);
                        aNi[nt] = __builtin_amdgcn_mfma_f32_16x16x32_bf16(afr, *(const short8*)(wr + 512 * 128), aNi[nt], 0, 0, 0);
                    }
                }
            } else {
#pragma unroll 2
                for (int kc = 0; kc < 512; kc += 32) {
                    short8 afr = *(const short8*)&sm.g.x_s[l15 * 520 + kc + q * 8];
#pragma unroll
                    for (int nt = 0; nt < 2; ++nt) {
                        const uint16_t* wr = wih + (size_t)(ew + nt * 16 + l15) * 512 + kc + q * 8;
                        aR[nt]  = __builtin_amdgcn_mfma_f32_16x16x32_bf16(afr, *(const short8*)wr, aR[nt], 0, 0, 0);
                        aZ[nt]  = __builtin_amdgcn_mfma_f32_16x16x32_bf16(afr, *(const short8*)(wr + 256 * 512), aZ[nt], 0, 0, 0);
                        aNi[nt] = __builtin_amdgcn_mfma_f32_16x16x32_bf16(afr, *(const short8*)(wr + 512 * 512), aNi[nt], 0, 0, 0);
                    }
                }
            }
#pragma unroll 2
            for (int kc = 0; kc < 256; kc += 32) {
                short8 afr = *(const short8*)&sm.g.h_s[l15 * 264 + kc + q * 8];
#pragma unroll
                for (int nt = 0; nt < 2; ++nt) {
                    const uint16_t* wr = whh + (size_t)(ew + nt * 16 + l15) * 256 + kc + q * 8;
                    aR[nt]  = __builtin_amdgcn_mfma_f32_16x16x32_bf16(afr, *(const short8*)wr, aR[nt], 0, 0, 0);
                    aZ[nt]  = __builtin_amdgcn_mfma_f32_16x16x32_bf16(afr, *(const short8*)(wr + 256 * 256), aZ[nt], 0, 0, 0);
                    aNh[nt] = __builtin_amdgcn_mfma_f32_16x16x32_bf16(afr, *(const short8*)(wr + 512 * 256), aNh[nt], 0, 0, 0);
                }
            }
            __syncthreads();   // all h_s reads done before overwrite
            // ---- epilogue: gates + state update ----
#pragma unroll
            for (int nt = 0; nt < 2; ++nt) {
                int e = ew + nt * 16 + l15;
#pragma unroll
                for (int r = 0; r < 4; ++r) {
                    float rr = sigmoidf_(aR[nt][r] + bR[nt]);
                    float zz = sigmoidf_(aZ[nt][r] + bZ[nt]);
                    float nn = tanhf(aNi[nt][r] + bN[nt] + rr * (aNh[nt][r] + bHN[nt]));
                    float hn = (1.f - zz) * nn + zz * hreg[nt][r];
                    hreg[nt][r] = hn;
                    sm.g.h_s[(q * 4 + r) * 264 + e] = f2bf(hn);
                }
            }
            __syncthreads();
            // ---- publish h(t) to ring (coalesced from h_s) ----
            {
                int r = tid >> 5, c0 = (tid & 31) * 8;
                *(int4*)(ring + ((size_t)((t & 7) * 6 + role) * NB + (b0 + r)) * NH + c0) =
                    *(const int4*)&sm.g.h_s[r * 264 + c0];
            }
            __syncthreads();   // barrier drains all waves' stores to L2
            if (tid == 0)
                __hip_atomic_store(&produced[PIDX(role, t, btile)], 1,
                                   __ATOMIC_RELEASE, __HIP_MEMORY_SCOPE_AGENT);
        }
        return;
    }

    // =================== attention stage ===================================
    const int lA = w / 3, nfA = w % 3;
    const float b1A = la_b1[lA * 48 + nfA * 16 + l15];
    const float w2A = la_w2[lA * 48 + nfA * 16 + l15];
    float b1B = 0.f, w2B = 0.f;
    if (w == 0) { b1B = la_b1[2 * 48 + 2 * 16 + l15]; w2B = la_w2[2 * 48 + 2 * 16 + l15]; }
    float nacc[16];
#pragma unroll
    for (int j = 0; j < 16; ++j) nacc[j] = 0.f;
    float m_r = -1e30f, d_r = 0.f;

    for (int t = 0; t < NT; ++t) {
        if (tid == 0) {
            const int* p4 = &produced[PIDX(4, t, btile)];
            const int* p5 = &produced[PIDX(5, t, btile)];
            while (__hip_atomic_load(p4, __ATOMIC_RELAXED, __HIP_MEMORY_SCOPE_AGENT) == 0)
                __builtin_amdgcn_s_sleep(1);
            while (__hip_atomic_load(p5, __ATOMIC_RELAXED, __HIP_MEMORY_SCOPE_AGENT) == 0)
                __builtin_amdgcn_s_sleep(1);
        }
        __syncthreads();
        // ---- stage all 6 states into hbf ----
#pragma unroll
        for (int j = 0; j < 6; ++j) {
            int u = tid + j * 512;
            int s = u >> 9, rem = u & 511;
            int r = rem >> 5, c0 = (rem & 31) * 8;
            const uint16_t* src =
                ring + ((size_t)((t & 7) * 6 + s) * NB + (b0 + r)) * NH + c0;
            int4 v = ld_coh16(src);
            *(int4*)&sm.a.hbf[(s * 16 + r) * 264 + c0] = v;
        }
        __syncthreads();
        if (tid == 0) {
#pragma unroll
            for (int s = 0; s < 6; ++s)
                __hip_atomic_fetch_add(&consumed[PIDX(s, t, btile)], 1,
                                       __ATOMIC_RELAXED, __HIP_MEMORY_SCOPE_AGENT);
        }
        // ---- job A: la(lA, nfA) ----
        {
            floatx4 ac = (floatx4){0.f, 0.f, 0.f, 0.f};
#pragma unroll 2
            for (int kc = 0; kc < 512; kc += 32) {
                int k = kc + q * 8;
                int s = 2 * lA + (k >= 256 ? 1 : 0);
                short8 afr = *(const short8*)&sm.a.hbf[(s * 16 + l15) * 264 + (k & 255)];
                const uint16_t* wr = law1_bf + (size_t)(lA * 48 + nfA * 16 + l15) * 512 + k;
                ac = __builtin_amdgcn_mfma_f32_16x16x32_bf16(afr, *(const short8*)wr, ac, 0, 0, 0);
            }
#pragma unroll
            for (int r = 0; r < 4; ++r) {
                float v = geluf_(ac[r] + b1A) * w2A;
                v += __shfl_xor(v, 1, 64);
                v += __shfl_xor(v, 2, 64);
                v += __shfl_xor(v, 4, 64);
                v += __shfl_xor(v, 8, 64);
                if (l15 == 0) sm.a.laP[lA][nfA][q * 4 + r] = v;
            }
        }
        // ---- job B ----
        if (w == 0) {           // la(2,2)
            floatx4 ac = (floatx4){0.f, 0.f, 0.f, 0.f};
#pragma unroll 2
            for (int kc = 0; kc < 512; kc += 32) {
                int k = kc + q * 8;
                int s = 4 + (k >= 256 ? 1 : 0);
                short8 afr = *(const short8*)&sm.a.hbf[(s * 16 + l15) * 264 + (k & 255)];
                const uint16_t* wr = law1_bf + (size_t)(2 * 48 + 2 * 16 + l15) * 512 + k;
                ac = __builtin_amdgcn_mfma_f32_16x16x32_bf16(afr, *(const short8*)wr, ac, 0, 0, 0);
            }
#pragma unroll
            for (int r = 0; r < 4; ++r) {
                float v = geluf_(ac[r] + b1B) * w2B;
                v += __shfl_xor(v, 1, 64);
                v += __shfl_xor(v, 2, 64);
                v += __shfl_xor(v, 4, 64);
                v += __shfl_xor(v, 8, 64);
                if (l15 == 0) sm.a.laP[2][2][q * 4 + r] = v;
            }
        } else if (w <= 4) {    // sa tile nf = w-1 (raw pre-acts)
            int nf = w - 1;
            floatx4 ac = (floatx4){0.f, 0.f, 0.f, 0.f};
#pragma unroll 2
            for (int kc = 0; kc < 512; kc += 32) {
                int k = kc + q * 8;
                int s = 4 + (k >= 256 ? 1 : 0);
                short8 afr = *(const short8*)&sm.a.hbf[(s * 16 + l15) * 264 + (k & 255)];
                const uint16_t* wr = saw1_bf + (size_t)(nf * 16 + l15) * 512 + k;
                ac = __builtin_amdgcn_mfma_f32_16x16x32_bf16(afr, *(const short8*)wr, ac, 0, 0, 0);
            }
#pragma unroll
            for (int r = 0; r < 4; ++r) sm.a.saT[nf][q * 4 + r][l15] = ac[r];
        }
        __syncthreads();
        // ---- combine: s and logit per row (wave 0) ----
        if (w == 0) {
            int row = l15;
            float sv = 0.f;
#pragma unroll
            for (int l = 0; l < 3; ++l)
                sv += sigmoidf_(sm.a.laP[l][0][row] + sm.a.laP[l][1][row] +
                                sm.a.laP[l][2][row] + la_b2[l]);
            float a2 = 0.f;
#pragma unroll
            for (int i = 0; i < 16; ++i) {
                int c = q * 16 + i;
                float pre = sv * sm.a.saT[q][row][i] + sa_b1[c];
                a2 += pre * sigmoidf_(pre) * sa_w2[c];
            }
            a2 += __shfl_xor(a2, 16, 64);
            a2 += __shfl_xor(a2, 32, 64);
            if (q == 0 && lane < 16) { sm.a.s_s[row] = sv; sm.a.lg_s[row] = a2 + sa_b2[0]; }
        }
        __syncthreads();
        // ---- online softmax update (wave w owns rows 2w, 2w+1) ----
        {
            int myrow = 2 * w + (lane >> 5);
            int ci = lane & 31;
            float lg = sm.a.lg_s[myrow], sv = sm.a.s_s[myrow];
            float mn = fmaxf(m_r, lg);
            float cs = expf(m_r - mn);
            float e = expf(lg - mn);
            m_r = mn;
            d_r = d_r * cs + e;
            float wf = e * sv;
            int st = 4 + (ci >> 4);
            int c0 = (ci & 15) * 16;
            const uint16_t* hp = &sm.a.hbf[(size_t)(st * 16 + myrow) * 264 + c0];
            short8 o0 = *(const short8*)hp;
            short8 o1 = *(const short8*)(hp + 8);
#pragma unroll
            for (int j = 0; j < 8; ++j) {
                nacc[j]     = nacc[j] * cs + wf * bf2f((uint16_t)o0[j]);
                nacc[8 + j] = nacc[8 + j] * cs + wf * bf2f((uint16_t)o1[j]);
            }
        }
        __syncthreads();   // protect hbf/s_s before next step's staging
    }

    // ---- finalize: context -> LN -> FC ----
    {
        int myrow = 2 * w + (lane >> 5);
        int ci = lane & 31;
        float dinv = 1.f / d_r;
        float cv[16];
        float s1 = 0.f, s2 = 0.f;
#pragma unroll
        for (int j = 0; j < 16; ++j) {
            cv[j] = nacc[j] * dinv;
            s1 += cv[j];
            s2 += cv[j] * cv[j];
        }
        s1 += __shfl_xor(s1, 1, 64);  s2 += __shfl_xor(s2, 1, 64);
        s1 += __shfl_xor(s1, 2, 64);  s2 += __shfl_xor(s2, 2, 64);
        s1 += __shfl_xor(s1, 4, 64);  s2 += __shfl_xor(s2, 4, 64);
        s1 += __shfl_xor(s1, 8, 64);  s2 += __shfl_xor(s2, 8, 64);
        s1 += __shfl_xor(s1, 16, 64); s2 += __shfl_xor(s2, 16, 64);
        float mean = s1 / 512.f;
        float var = s2 / 512.f - mean * mean;
        float rstd = rsqrtf(var + 1e-5f);
        float p0 = 0.f, p1 = 0.f;
#pragma unroll
        for (int j = 0; j < 16; ++j) {
            int g = ci * 16 + j;
            float nv = (cv[j] - mean) * rstd * ln_g[g] + ln_b[g];
            p0 += nv * fc_w[g];
            p1 += nv * fc_w[512 + g];
        }
        p0 += __shfl_xor(p0, 1, 64);  p1 += __shfl_xor(p1, 1, 64);
        p0 += __shfl_xor(p0, 2, 64);  p1 += __shfl_xor(p1, 2, 64);
        p0 += __shfl_xor(p0, 4, 64);  p1 += __shfl_xor(p1, 4, 64);
        p0 += __shfl_xor(p0, 8, 64);  p1 += __shfl_xor(p1, 8, 64);
        p0 += __shfl_xor(p0, 16, 64); p1 += __shfl_xor(p1, 16, 64);
        if ((lane & 31) == 0) {
            out[(b0 + myrow) * 2 + 0] = p0 + fc_b[0];
            out[(b0 + myrow) * 2 + 1] = p1 + fc_b[1];
        }
    }
}

// ---------------------------------------------------------------------------
extern "C" void kernel_launch(void* const* d_in, const int* in_sizes, int n_in,
                              void* d_out, int out_size, void* d_ws, size_t ws_size,
                              hipStream_t stream) {
    const float* x     = (const float*)d_in[0];
    const float* enc_w = (const float*)d_in[1];
    const float* enc_b = (const float*)d_in[2];
    const float* wih0  = (const float*)d_in[3];
    const float* wihL  = (const float*)d_in[4];
    const float* whh   = (const float*)d_in[5];
    const float* bih   = (const float*)d_in[6];
    const float* bhh   = (const float*)d_in[7];
    const float* la_w1 = (const float*)d_in[8];
    const float* la_b1 = (const float*)d_in[9];
    const float* la_w2 = (const float*)d_in[10];
    const float* la_b2 = (const float*)d_in[11];
    const float* sa_w1 = (const float*)d_in[12];
    const float* sa_b1 = (const float*)d_in[13];
    const float* sa_w2 = (const float*)d_in[14];
    const float* sa_b2 = (const float*)d_in[15];
    const float* ln_g  = (const float*)d_in[16];
    const float* ln_b  = (const float*)d_in[17];
    const float* fc_w  = (const float*)d_in[18];
    const float* fc_b  = (const float*)d_in[19];
    float* out = (float*)d_out;

    uint8_t* wsb = (uint8_t*)d_ws;
    size_t off = 0;
    auto alloc = [&](size_t bytes) -> void* {
        void* p = wsb + off;
        off += (bytes + 255) & ~(size_t)255;
        return p;
    };
    uint16_t* enc_bf  = (uint16_t*)alloc((size_t)NB * 32768 * 2);         // 33.55 MB
    uint16_t* wih0_bf = (uint16_t*)alloc((size_t)2 * NG * 128 * 2);       // 0.39 MB
    uint16_t* wihL_bf = (uint16_t*)alloc((size_t)2 * 2 * NG * 512 * 2);   // 3.15 MB
    uint16_t* whh_bf  = (uint16_t*)alloc((size_t)3 * 2 * NG * 256 * 2);   // 2.36 MB
    uint16_t* law1_bf = (uint16_t*)alloc((size_t)3 * 48 * 512 * 2);       // 0.15 MB
    uint16_t* saw1_bf = (uint16_t*)alloc((size_t)64 * 512 * 2);           // 0.07 MB
    uint16_t* ring    = (uint16_t*)alloc((size_t)R_RING * 6 * NB * NH * 2); // 12.58 MB
    int*      produced= (int*)alloc((size_t)6 * NT * 32 * 4);             // 0.19 MB
    int*      consumed= (int*)alloc((size_t)6 * NT * 32 * 4);             // 0.19 MB
    // total ~52.7 MB

    if (ws_size < off) {
        k_sentinel<<<4, 256, 0, stream>>>(out);
        return;
    }

    auto cvt = [&](const float* s, uint16_t* dmem, int n) {
        int n4 = n / 4;
        k_cvt<<<(n4 + 255) / 256, 256, 0, stream>>>(s, dmem, n4);
    };
    cvt(wih0, wih0_bf, 196608);
    cvt(wihL, wihL_bf, 1572864);
    cvt(whh, whh_bf, 1179648);
    cvt(la_w1, law1_bf, 73728);
    cvt(sa_w1, saw1_bf, 32768);
    // zero produced+consumed (contiguous, 98304 ints = 24576 float4)
    k_zero<<<96, 256, 0, stream>>>((float*)produced, 24576);

    k_encoder<<<dim3(256, 4), 256, 0, stream>>>(x, enc_w, enc_b, enc_bf);

    k_scan<<<256, BTH, 0, stream>>>(enc_bf, wih0_bf, wihL_bf, whh_bf,
                                    bih, bhh, law1_bf, la_b1, la_w2, la_b2,
                                    saw1_bf, sa_b1, sa_w2, sa_b2,
                                    ln_g, ln_b, fc_w, fc_b,
                                    ring, produced, consumed, out);
}

// Round 6
// 9217.510 us; speedup vs baseline: 15.0532x; 1.1390x over previous
//
#include <hip/hip_runtime.h>
#include <stdint.h>

// ---------------------------------------------------------------------------
// GRUClassifier stage-pipelined version (round 5 = round 4 + asm type fix).
// 7 pipeline stages ((l,d) x 6 GRU + attention) x 32 batch tiles = 224 blocks.
// role = blockIdx%8 pins each stage to one XCD => stage weights stay in its L2
// (validated round 3: FETCH 7.7GB -> 0.5GB).
// Handoff without buffer_wbl2: ring payload stores are write-through (sc0 sc1)
// so no dirty L2 lines; __syncthreads drains vmcnt; flag is a RELAXED atomic
// store. Consumer: relaxed flag spin + BATCHED sc0/sc1 coherent loads.
// asm data operands use ext_vector types (HIP int4 struct fails 'v' input
// constraint: "indirect register inputs").
// Numerics (validated round 2): bf16 MFMA inputs, fp32 hidden carry.
// ---------------------------------------------------------------------------

typedef short short8 __attribute__((ext_vector_type(8)));
typedef float floatx4 __attribute__((ext_vector_type(4)));
typedef int intx4 __attribute__((ext_vector_type(4)));
typedef unsigned long long u64;

#define NB 512
#define NT 256
#define NH 256
#define NG 768
#define R_RING 8
#define BTH 512

__device__ __forceinline__ float bf2f(uint16_t v) {
    uint32_t u = ((uint32_t)v) << 16;
    float f;
    __builtin_memcpy(&f, &u, 4);
    return f;
}
__device__ __forceinline__ uint16_t f2bf(float f) {
    uint32_t u;
    __builtin_memcpy(&u, &f, 4);
    uint32_t r = (u + 0x7FFFu + ((u >> 16) & 1u)) >> 16;
    return (uint16_t)r;
}
__device__ __forceinline__ u64 pack4bf(float4 v) {
    u64 a = f2bf(v.x), b = f2bf(v.y), c = f2bf(v.z), d = f2bf(v.w);
    return a | (b << 16) | (c << 32) | (d << 48);
}
__device__ __forceinline__ float sigmoidf_(float x) { return 1.f / (1.f + expf(-x)); }
__device__ __forceinline__ float geluf_(float x) { return 0.5f * x * (1.f + erff(x * 0.70710678118f)); }

// write-through 16B store: data to coherence point, leaves no dirty L2 line
__device__ __forceinline__ void st_coh16(void* p, intx4 v) {
    asm volatile("global_store_dwordx4 %0, %1, off sc0 sc1"
                 :: "v"(p), "v"(v) : "memory");
}
// batched coherent loads: issue all, single waitcnt
__device__ __forceinline__ void ld_coh16x2(const void* p0, const void* p1,
                                           intx4& v0, intx4& v1) {
    asm volatile(
        "global_load_dwordx4 %0, %2, off sc0 sc1\n\t"
        "global_load_dwordx4 %1, %3, off sc0 sc1\n\t"
        "s_waitcnt vmcnt(0)"
        : "=&v"(v0), "=&v"(v1)
        : "v"(p0), "v"(p1)
        : "memory");
}
__device__ __forceinline__ void ld_coh16x6(
    const void* p0, const void* p1, const void* p2,
    const void* p3, const void* p4, const void* p5,
    intx4& v0, intx4& v1, intx4& v2, intx4& v3, intx4& v4, intx4& v5) {
    asm volatile(
        "global_load_dwordx4 %0, %6, off sc0 sc1\n\t"
        "global_load_dwordx4 %1, %7, off sc0 sc1\n\t"
        "global_load_dwordx4 %2, %8, off sc0 sc1\n\t"
        "global_load_dwordx4 %3, %9, off sc0 sc1\n\t"
        "global_load_dwordx4 %4, %10, off sc0 sc1\n\t"
        "global_load_dwordx4 %5, %11, off sc0 sc1\n\t"
        "s_waitcnt vmcnt(0)"
        : "=&v"(v0), "=&v"(v1), "=&v"(v2), "=&v"(v3), "=&v"(v4), "=&v"(v5)
        : "v"(p0), "v"(p1), "v"(p2), "v"(p3), "v"(p4), "v"(p5)
        : "memory");
}

#define PIDX(s, t, b) ((((s) * NT) + (t)) * 32 + (b))

// ---------------- small utility kernels ------------------------------------
__global__ void k_cvt(const float* __restrict__ src, uint16_t* __restrict__ dst, int n4) {
    int i = blockIdx.x * blockDim.x + threadIdx.x;
    if (i < n4) {
        float4 v = ((const float4*)src)[i];
        ushort4 o;
        o.x = f2bf(v.x); o.y = f2bf(v.y); o.z = f2bf(v.z); o.w = f2bf(v.w);
        ((ushort4*)dst)[i] = o;
    }
}

__global__ void k_zero(float* __restrict__ p, int n4) {
    int i = blockIdx.x * blockDim.x + threadIdx.x;
    if (i < n4) ((float4*)p)[i] = make_float4(0.f, 0.f, 0.f, 0.f);
}

__global__ void k_sentinel(float* __restrict__ out) {
    int i = blockIdx.x * blockDim.x + threadIdx.x;
    if (i < 1024) out[i] = -99999.0f;
}

// ---------------- encoder: encoded = mish(x @ enc_w^T + enc_b), bf16 out ----
__global__ __launch_bounds__(256) void k_encoder(
    const float* __restrict__ x, const float* __restrict__ enc_w,
    const float* __restrict__ enc_b, uint16_t* __restrict__ enc_out) {
    const int tid = threadIdx.x;
    const int lane = tid & 63, wid = tid >> 6;
    const int q = lane >> 4, l15 = lane & 15;
    const int wm = wid >> 1, wj = wid & 1;
    const int j0 = blockIdx.x * 128, b0 = blockIdx.y * 128;

    __shared__ uint16_t a_s[128 * 72];
    __shared__ uint16_t w_s[128 * 72];

#pragma unroll
    for (int jj = 0; jj < 8; ++jj) {
        int u = tid + jj * 256;
        int r = u >> 4, c4 = (u & 15) * 4;
        float4 va = *(const float4*)&x[(size_t)(b0 + r) * 64 + c4];
        float4 vw = *(const float4*)&enc_w[(size_t)(j0 + r) * 64 + c4];
        *(u64*)&a_s[r * 72 + c4] = pack4bf(va);
        *(u64*)&w_s[r * 72 + c4] = pack4bf(vw);
    }
    __syncthreads();

    floatx4 acc[4][4];
#pragma unroll
    for (int mi = 0; mi < 4; ++mi)
#pragma unroll
        for (int nf = 0; nf < 4; ++nf) acc[mi][nf] = (floatx4){0.f, 0.f, 0.f, 0.f};

#pragma unroll
    for (int kc = 0; kc < 2; ++kc) {
        short8 af[4], bfg[4];
#pragma unroll
        for (int mi = 0; mi < 4; ++mi)
            af[mi] = *(const short8*)&a_s[(wm * 64 + mi * 16 + l15) * 72 + kc * 32 + q * 8];
#pragma unroll
        for (int nf = 0; nf < 4; ++nf)
            bfg[nf] = *(const short8*)&w_s[(wj * 64 + nf * 16 + l15) * 72 + kc * 32 + q * 8];
#pragma unroll
        for (int mi = 0; mi < 4; ++mi)
#pragma unroll
            for (int nf = 0; nf < 4; ++nf)
                acc[mi][nf] = __builtin_amdgcn_mfma_f32_16x16x32_bf16(af[mi], bfg[nf], acc[mi][nf], 0, 0, 0);
    }

#pragma unroll
    for (int nf = 0; nf < 4; ++nf) {
        int j = j0 + wj * 64 + nf * 16 + l15;
        float eb = enc_b[j];
#pragma unroll
        for (int mi = 0; mi < 4; ++mi)
#pragma unroll
            for (int r = 0; r < 4; ++r) {
                int b = b0 + wm * 64 + mi * 16 + q * 4 + r;
                float v = acc[mi][nf][r] + eb;
                float sp = (v > 20.f) ? v : log1pf(expf(v));
                float m = v * tanhf(sp);
                enc_out[(size_t)b * 32768 + j] = f2bf(m);
            }
    }
}

// ---------------- shared memory layouts ------------------------------------
struct SGru {
    uint16_t x_s[16 * 520];   // gi input, [row][col]
    uint16_t h_s[16 * 264];   // own h(t-1) bf16 shadow
};
struct SAtt {
    uint16_t hbf[6 * 16 * 264];
    float laP[3][3][16];
    float saT[4][16][17];
    float s_s[16], lg_s[16];
};
union SMem { SGru g; SAtt a; };

// ---------------- stage-pipelined scan kernel ------------------------------
// grid 256 x 512 thr. role = blockIdx%8 (0..5 GRU (l,d), 6 attn, 7 idle).
// btile = blockIdx/8 owns batch rows [btile*16, btile*16+16).
__global__ __launch_bounds__(BTH) void k_scan(
    const uint16_t* __restrict__ enc_bf,
    const uint16_t* __restrict__ wih0_bf, const uint16_t* __restrict__ wihL_bf,
    const uint16_t* __restrict__ whh_bf,
    const float* __restrict__ bih, const float* __restrict__ bhh,
    const uint16_t* __restrict__ law1_bf, const float* __restrict__ la_b1,
    const float* __restrict__ la_w2, const float* __restrict__ la_b2,
    const uint16_t* __restrict__ saw1_bf, const float* __restrict__ sa_b1,
    const float* __restrict__ sa_w2, const float* __restrict__ sa_b2,
    const float* __restrict__ ln_g, const float* __restrict__ ln_b,
    const float* __restrict__ fc_w, const float* __restrict__ fc_b,
    uint16_t* __restrict__ ring, int* produced, int* consumed,
    float* __restrict__ out) {
    const int role = blockIdx.x & 7;
    const int btile = blockIdx.x >> 3;
    if (role == 7) return;
    const int tid = threadIdx.x;
    const int w = tid >> 6;
    const int lane = tid & 63;
    const int q = lane >> 4, l15 = lane & 15;
    const int b0 = btile * 16;

    __shared__ SMem sm;

    if (role < 6) {
        // =================== GRU stage (l, d) ==============================
        const int l = role >> 1, dd = role & 1;
        const uint16_t* wih = (l == 0) ? wih0_bf + (size_t)dd * NG * 128
                                       : wihL_bf + (size_t)((l - 1) * 2 + dd) * NG * 512;
        const uint16_t* whh = whh_bf + (size_t)role * NG * 256;
        const int ew = w * 32;                   // wave e-slice (2 N-tiles)
        const int ncons_my = (l == 2) ? 1 : 3;

        for (int i = tid; i < 16 * 264; i += BTH) sm.g.h_s[i] = 0;

        float bR[2], bZ[2], bN[2], bHN[2];
        {
            int base = role * NG;
#pragma unroll
            for (int nt = 0; nt < 2; ++nt) {
                int e = ew + nt * 16 + l15;
                bR[nt] = bih[base + e] + bhh[base + e];
                bZ[nt] = bih[base + 256 + e] + bhh[base + 256 + e];
                bN[nt] = bih[base + 512 + e];
                bHN[nt] = bhh[base + 512 + e];
            }
        }
        float hreg[2][4];
#pragma unroll
        for (int nt = 0; nt < 2; ++nt)
#pragma unroll
            for (int r = 0; r < 4; ++r) hreg[nt][r] = 0.f;
        __syncthreads();

        for (int t = 0; t < NT; ++t) {
            // ---- waits: back-pressure + upstream flags (thread 0) ----
            if (tid == 0) {
                if (t >= R_RING) {
                    const int* cp = &consumed[PIDX(role, t - R_RING, btile)];
                    while (__hip_atomic_load(cp, __ATOMIC_RELAXED, __HIP_MEMORY_SCOPE_AGENT) < ncons_my)
                        __builtin_amdgcn_s_sleep(1);
                }
                if (l > 0) {
                    const int* p0 = &produced[PIDX(2 * (l - 1), t, btile)];
                    const int* p1 = &produced[PIDX(2 * (l - 1) + 1, t, btile)];
                    while (__hip_atomic_load(p0, __ATOMIC_RELAXED, __HIP_MEMORY_SCOPE_AGENT) == 0)
                        __builtin_amdgcn_s_sleep(1);
                    while (__hip_atomic_load(p1, __ATOMIC_RELAXED, __HIP_MEMORY_SCOPE_AGENT) == 0)
                        __builtin_amdgcn_s_sleep(1);
                }
            }
            __syncthreads();
            // ---- stage gi input into x_s ----
            if (l == 0) {
                if (tid < 256) {
                    int r = tid >> 4, c0 = (tid & 15) * 8;
                    *(intx4*)&sm.g.x_s[r * 520 + c0] =
                        *(const intx4*)&enc_bf[((size_t)(b0 + r) << 15) + t * 128 + c0];
                }
            } else {
                int r0 = tid >> 6, c0 = (tid & 63) * 8;
                int r1 = r0 + 8;
                int s = 2 * (l - 1) + (c0 >= 256 ? 1 : 0);
                const uint16_t* src0 =
                    ring + ((size_t)((t & 7) * 6 + s) * NB + (b0 + r0)) * NH + (c0 & 255);
                const uint16_t* src1 =
                    ring + ((size_t)((t & 7) * 6 + s) * NB + (b0 + r1)) * NH + (c0 & 255);
                intx4 v0, v1;
                ld_coh16x2(src0, src1, v0, v1);
                *(intx4*)&sm.g.x_s[r0 * 520 + c0] = v0;
                *(intx4*)&sm.g.x_s[r1 * 520 + c0] = v1;
            }
            __syncthreads();
            if (l > 0 && tid == 0) {
                __hip_atomic_fetch_add(&consumed[PIDX(2 * (l - 1), t, btile)], 1,
                                       __ATOMIC_RELAXED, __HIP_MEMORY_SCOPE_AGENT);
                __hip_atomic_fetch_add(&consumed[PIDX(2 * (l - 1) + 1, t, btile)], 1,
                                       __ATOMIC_RELAXED, __HIP_MEMORY_SCOPE_AGENT);
            }
            // ---- compute: gi + gh ----
            floatx4 aR[2], aZ[2], aNi[2], aNh[2];
#pragma unroll
            for (int nt = 0; nt < 2; ++nt) {
                floatx4 z = (floatx4){0.f, 0.f, 0.f, 0.f};
                aR[nt] = z; aZ[nt] = z; aNi[nt] = z; aNh[nt] = z;
            }
            if (l == 0) {
#pragma unroll 2
                for (int kc = 0; kc < 128; kc += 32) {
                    short8 afr = *(const short8*)&sm.g.x_s[l15 * 520 + kc + q * 8];
#pragma unroll
                    for (int nt = 0; nt < 2; ++nt) {
                        const uint16_t* wr = wih + (size_t)(ew + nt * 16 + l15) * 128 + kc + q * 8;
                        aR[nt]  = __builtin_amdgcn_mfma_f32_16x16x32_bf16(afr, *(const short8*)wr, aR[nt], 0, 0, 0);
                        aZ[nt]  = __builtin_amdgcn_mfma_f32_16x16x32_bf16(afr, *(const short8*)(wr + 256 * 128), aZ[nt], 0, 0, 0);
                        aNi[nt] = __builtin_amdgcn_mfma_f32_16x16x32_bf16(afr, *(const short8*)(wr + 512 * 128), aNi[nt], 0, 0, 0);
                    }
                }
            } else {
#pragma unroll 2
                for (int kc = 0; kc < 512; kc += 32) {
                    short8 afr = *(const short8*)&sm.g.x_s[l15 * 520 + kc + q * 8];
#pragma unroll
                    for (int nt = 0; nt < 2; ++nt) {
                        const uint16_t* wr = wih + (size_t)(ew + nt * 16 + l15) * 512 + kc + q * 8;
                        aR[nt]  = __builtin_amdgcn_mfma_f32_16x16x32_bf16(afr, *(const short8*)wr, aR[nt], 0, 0, 0);
                        aZ[nt]  = __builtin_amdgcn_mfma_f32_16x16x32_bf16(afr, *(const short8*)(wr + 256 * 512), aZ[nt], 0, 0, 0);
                        aNi[nt] = __builtin_amdgcn_mfma_f32_16x16x32_bf16(afr, *(const short8*)(wr + 512 * 512), aNi[nt], 0, 0, 0);
                    }
                }
            }
#pragma unroll 2
            for (int kc = 0; kc < 256; kc += 32) {
                short8 afr = *(const short8*)&sm.g.h_s[l15 * 264 + kc + q * 8];
#pragma unroll
                for (int nt = 0; nt < 2; ++nt) {
                    const uint16_t* wr = whh + (size_t)(ew + nt * 16 + l15) * 256 + kc + q * 8;
                    aR[nt]  = __builtin_amdgcn_mfma_f32_16x16x32_bf16(afr, *(const short8*)wr, aR[nt], 0, 0, 0);
                    aZ[nt]  = __builtin_amdgcn_mfma_f32_16x16x32_bf16(afr, *(const short8*)(wr + 256 * 256), aZ[nt], 0, 0, 0);
                    aNh[nt] = __builtin_amdgcn_mfma_f32_16x16x32_bf16(afr, *(const short8*)(wr + 512 * 256), aNh[nt], 0, 0, 0);
                }
            }
            __syncthreads();   // all h_s reads done before overwrite
            // ---- epilogue: gates + state update ----
#pragma unroll
            for (int nt = 0; nt < 2; ++nt) {
                int e = ew + nt * 16 + l15;
#pragma unroll
                for (int r = 0; r < 4; ++r) {
                    float rr = sigmoidf_(aR[nt][r] + bR[nt]);
                    float zz = sigmoidf_(aZ[nt][r] + bZ[nt]);
                    float nn = tanhf(aNi[nt][r] + bN[nt] + rr * (aNh[nt][r] + bHN[nt]));
                    float hn = (1.f - zz) * nn + zz * hreg[nt][r];
                    hreg[nt][r] = hn;
                    sm.g.h_s[(q * 4 + r) * 264 + e] = f2bf(hn);
                }
            }
            __syncthreads();
            // ---- publish h(t) to ring: write-through stores ----
            {
                int r = tid >> 5, c0 = (tid & 31) * 8;
                st_coh16(ring + ((size_t)((t & 7) * 6 + role) * NB + (b0 + r)) * NH + c0,
                         *(const intx4*)&sm.g.h_s[r * 264 + c0]);
            }
            __syncthreads();   // drains vmcnt: all waves' stores acked at coherence point
            if (tid == 0) {
                asm volatile("s_waitcnt vmcnt(0)" ::: "memory");
                __hip_atomic_store(&produced[PIDX(role, t, btile)], 1,
                                   __ATOMIC_RELAXED, __HIP_MEMORY_SCOPE_AGENT);
            }
        }
        return;
    }

    // =================== attention stage ===================================
    const int lA = w / 3, nfA = w % 3;
    const float b1A = la_b1[lA * 48 + nfA * 16 + l15];
    const float w2A = la_w2[lA * 48 + nfA * 16 + l15];
    float b1B = 0.f, w2B = 0.f;
    if (w == 0) { b1B = la_b1[2 * 48 + 2 * 16 + l15]; w2B = la_w2[2 * 48 + 2 * 16 + l15]; }
    float nacc[16];
#pragma unroll
    for (int j = 0; j < 16; ++j) nacc[j] = 0.f;
    float m_r = -1e30f, d_r = 0.f;

    for (int t = 0; t < NT; ++t) {
        if (tid == 0) {
            const int* p4 = &produced[PIDX(4, t, btile)];
            const int* p5 = &produced[PIDX(5, t, btile)];
            while (__hip_atomic_load(p4, __ATOMIC_RELAXED, __HIP_MEMORY_SCOPE_AGENT) == 0)
                __builtin_amdgcn_s_sleep(1);
            while (__hip_atomic_load(p5, __ATOMIC_RELAXED, __HIP_MEMORY_SCOPE_AGENT) == 0)
                __builtin_amdgcn_s_sleep(1);
        }
        __syncthreads();
        // ---- stage all 6 states into hbf (batched coherent loads) ----
        {
            int r = tid >> 5, c0 = (tid & 31) * 8;
            const uint16_t* base = ring + (size_t)(t & 7) * 6 * NB * NH;
            const uint16_t* s0 = base + ((size_t)0 * NB + (b0 + r)) * NH + c0;
            const uint16_t* s1 = base + ((size_t)1 * NB + (b0 + r)) * NH + c0;
            const uint16_t* s2 = base + ((size_t)2 * NB + (b0 + r)) * NH + c0;
            const uint16_t* s3 = base + ((size_t)3 * NB + (b0 + r)) * NH + c0;
            const uint16_t* s4 = base + ((size_t)4 * NB + (b0 + r)) * NH + c0;
            const uint16_t* s5 = base + ((size_t)5 * NB + (b0 + r)) * NH + c0;
            intx4 v0, v1, v2, v3, v4, v5;
            ld_coh16x6(s0, s1, s2, s3, s4, s5, v0, v1, v2, v3, v4, v5);
            *(intx4*)&sm.a.hbf[(0 * 16 + r) * 264 + c0] = v0;
            *(intx4*)&sm.a.hbf[(1 * 16 + r) * 264 + c0] = v1;
            *(intx4*)&sm.a.hbf[(2 * 16 + r) * 264 + c0] = v2;
            *(intx4*)&sm.a.hbf[(3 * 16 + r) * 264 + c0] = v3;
            *(intx4*)&sm.a.hbf[(4 * 16 + r) * 264 + c0] = v4;
            *(intx4*)&sm.a.hbf[(5 * 16 + r) * 264 + c0] = v5;
        }
        __syncthreads();
        if (tid == 0) {
#pragma unroll
            for (int s = 0; s < 6; ++s)
                __hip_atomic_fetch_add(&consumed[PIDX(s, t, btile)], 1,
                                       __ATOMIC_RELAXED, __HIP_MEMORY_SCOPE_AGENT);
        }
        // ---- job A: la(lA, nfA) ----
        {
            floatx4 ac = (floatx4){0.f, 0.f, 0.f, 0.f};
#pragma unroll 2
            for (int kc = 0; kc < 512; kc += 32) {
                int k = kc + q * 8;
                int s = 2 * lA + (k >= 256 ? 1 : 0);
                short8 afr = *(const short8*)&sm.a.hbf[(s * 16 + l15) * 264 + (k & 255)];
                const uint16_t* wr = law1_bf + (size_t)(lA * 48 + nfA * 16 + l15) * 512 + k;
                ac = __builtin_amdgcn_mfma_f32_16x16x32_bf16(afr, *(const short8*)wr, ac, 0, 0, 0);
            }
#pragma unroll
            for (int r = 0; r < 4; ++r) {
                float v = geluf_(ac[r] + b1A) * w2A;
                v += __shfl_xor(v, 1, 64);
                v += __shfl_xor(v, 2, 64);
                v += __shfl_xor(v, 4, 64);
                v += __shfl_xor(v, 8, 64);
                if (l15 == 0) sm.a.laP[lA][nfA][q * 4 + r] = v;
            }
        }
        // ---- job B ----
        if (w == 0) {           // la(2,2)
            floatx4 ac = (floatx4){0.f, 0.f, 0.f, 0.f};
#pragma unroll 2
            for (int kc = 0; kc < 512; kc += 32) {
                int k = kc + q * 8;
                int s = 4 + (k >= 256 ? 1 : 0);
                short8 afr = *(const short8*)&sm.a.hbf[(s * 16 + l15) * 264 + (k & 255)];
                const uint16_t* wr = law1_bf + (size_t)(2 * 48 + 2 * 16 + l15) * 512 + k;
                ac = __builtin_amdgcn_mfma_f32_16x16x32_bf16(afr, *(const short8*)wr, ac, 0, 0, 0);
            }
#pragma unroll
            for (int r = 0; r < 4; ++r) {
                float v = geluf_(ac[r] + b1B) * w2B;
                v += __shfl_xor(v, 1, 64);
                v += __shfl_xor(v, 2, 64);
                v += __shfl_xor(v, 4, 64);
                v += __shfl_xor(v, 8, 64);
                if (l15 == 0) sm.a.laP[2][2][q * 4 + r] = v;
            }
        } else if (w <= 4) {    // sa tile nf = w-1 (raw pre-acts)
            int nf = w - 1;
            floatx4 ac = (floatx4){0.f, 0.f, 0.f, 0.f};
#pragma unroll 2
            for (int kc = 0; kc < 512; kc += 32) {
                int k = kc + q * 8;
                int s = 4 + (k >= 256 ? 1 : 0);
                short8 afr = *(const short8*)&sm.a.hbf[(s * 16 + l15) * 264 + (k & 255)];
                const uint16_t* wr = saw1_bf + (size_t)(nf * 16 + l15) * 512 + k;
                ac = __builtin_amdgcn_mfma_f32_16x16x32_bf16(afr, *(const short8*)wr, ac, 0, 0, 0);
            }
#pragma unroll
            for (int r = 0; r < 4; ++r) sm.a.saT[nf][q * 4 + r][l15] = ac[r];
        }
        __syncthreads();
        // ---- combine: s and logit per row (wave 0) ----
        if (w == 0) {
            int row = l15;
            float sv = 0.f;
#pragma unroll
            for (int l = 0; l < 3; ++l)
                sv += sigmoidf_(sm.a.laP[l][0][row] + sm.a.laP[l][1][row] +
                                sm.a.laP[l][2][row] + la_b2[l]);
            float a2 = 0.f;
#pragma unroll
            for (int i = 0; i < 16; ++i) {
                int c = q * 16 + i;
                float pre = sv * sm.a.saT[q][row][i] + sa_b1[c];
                a2 += pre * sigmoidf_(pre) * sa_w2[c];
            }
            a2 += __shfl_xor(a2, 16, 64);
            a2 += __shfl_xor(a2, 32, 64);
            if (q == 0 && lane < 16) { sm.a.s_s[row] = sv; sm.a.lg_s[row] = a2 + sa_b2[0]; }
        }
        __syncthreads();
        // ---- online softmax update (wave w owns rows 2w, 2w+1) ----
        {
            int myrow = 2 * w + (lane >> 5);
            int ci = lane & 31;
            float lg = sm.a.lg_s[myrow], sv = sm.a.s_s[myrow];
            float mn = fmaxf(m_r, lg);
            float cs = expf(m_r - mn);
            float e = expf(lg - mn);
            m_r = mn;
            d_r = d_r * cs + e;
            float wf = e * sv;
            int st = 4 + (ci >> 4);
            int c0 = (ci & 15) * 16;
            const uint16_t* hp = &sm.a.hbf[(size_t)(st * 16 + myrow) * 264 + c0];
            short8 o0 = *(const short8*)hp;
            short8 o1 = *(const short8*)(hp + 8);
#pragma unroll
            for (int j = 0; j < 8; ++j) {
                nacc[j]     = nacc[j] * cs + wf * bf2f((uint16_t)o0[j]);
                nacc[8 + j] = nacc[8 + j] * cs + wf * bf2f((uint16_t)o1[j]);
            }
        }
        __syncthreads();   // protect hbf/s_s before next step's staging
    }

    // ---- finalize: context -> LN -> FC ----
    {
        int myrow = 2 * w + (lane >> 5);
        int ci = lane & 31;
        float dinv = 1.f / d_r;
        float cv[16];
        float s1 = 0.f, s2 = 0.f;
#pragma unroll
        for (int j = 0; j < 16; ++j) {
            cv[j] = nacc[j] * dinv;
            s1 += cv[j];
            s2 += cv[j] * cv[j];
        }
        s1 += __shfl_xor(s1, 1, 64);  s2 += __shfl_xor(s2, 1, 64);
        s1 += __shfl_xor(s1, 2, 64);  s2 += __shfl_xor(s2, 2, 64);
        s1 += __shfl_xor(s1, 4, 64);  s2 += __shfl_xor(s2, 4, 64);
        s1 += __shfl_xor(s1, 8, 64);  s2 += __shfl_xor(s2, 8, 64);
        s1 += __shfl_xor(s1, 16, 64); s2 += __shfl_xor(s2, 16, 64);
        float mean = s1 / 512.f;
        float var = s2 / 512.f - mean * mean;
        float rstd = rsqrtf(var + 1e-5f);
        float p0 = 0.f, p1 = 0.f;
#pragma unroll
        for (int j = 0; j < 16; ++j) {
            int g = ci * 16 + j;
            float nv = (cv[j] - mean) * rstd * ln_g[g] + ln_b[g];
            p0 += nv * fc_w[g];
            p1 += nv * fc_w[512 + g];
        }
        p0 += __shfl_xor(p0, 1, 64);  p1 += __shfl_xor(p1, 1, 64);
        p0 += __shfl_xor(p0, 2, 64);  p1 += __shfl_xor(p1, 2, 64);
        p0 += __shfl_xor(p0, 4, 64);  p1 += __shfl_xor(p1, 4, 64);
        p0 += __shfl_xor(p0, 8, 64);  p1 += __shfl_xor(p1, 8, 64);
        p0 += __shfl_xor(p0, 16, 64); p1 += __shfl_xor(p1, 16, 64);
        if ((lane & 31) == 0) {
            out[(b0 + myrow) * 2 + 0] = p0 + fc_b[0];
            out[(b0 + myrow) * 2 + 1] = p1 + fc_b[1];
        }
    }
}

// ---------------------------------------------------------------------------
extern "C" void kernel_launch(void* const* d_in, const int* in_sizes, int n_in,
                              void* d_out, int out_size, void* d_ws, size_t ws_size,
                              hipStream_t stream) {
    const float* x     = (const float*)d_in[0];
    const float* enc_w = (const float*)d_in[1];
    const float* enc_b = (const float*)d_in[2];
    const float* wih0  = (const float*)d_in[3];
    const float* wihL  = (const float*)d_in[4];
    const float* whh   = (const float*)d_in[5];
    const float* bih   = (const float*)d_in[6];
    const float* bhh   = (const float*)d_in[7];
    const float* la_w1 = (const float*)d_in[8];
    const float* la_b1 = (const float*)d_in[9];
    const float* la_w2 = (const float*)d_in[10];
    const float* la_b2 = (const float*)d_in[11];
    const float* sa_w1 = (const float*)d_in[12];
    const float* sa_b1 = (const float*)d_in[13];
    const float* sa_w2 = (const float*)d_in[14];
    const float* sa_b2 = (const float*)d_in[15];
    const float* ln_g  = (const float*)d_in[16];
    const float* ln_b  = (const float*)d_in[17];
    const float* fc_w  = (const float*)d_in[18];
    const float* fc_b  = (const float*)d_in[19];
    float* out = (float*)d_out;

    uint8_t* wsb = (uint8_t*)d_ws;
    size_t off = 0;
    auto alloc = [&](size_t bytes) -> void* {
        void* p = wsb + off;
        off += (bytes + 255) & ~(size_t)255;
        return p;
    };
    uint16_t* enc_bf  = (uint16_t*)alloc((size_t)NB * 32768 * 2);         // 33.55 MB
    uint16_t* wih0_bf = (uint16_t*)alloc((size_t)2 * NG * 128 * 2);       // 0.39 MB
    uint16_t* wihL_bf = (uint16_t*)alloc((size_t)2 * 2 * NG * 512 * 2);   // 3.15 MB
    uint16_t* whh_bf  = (uint16_t*)alloc((size_t)3 * 2 * NG * 256 * 2);   // 2.36 MB
    uint16_t* law1_bf = (uint16_t*)alloc((size_t)3 * 48 * 512 * 2);       // 0.15 MB
    uint16_t* saw1_bf = (uint16_t*)alloc((size_t)64 * 512 * 2);           // 0.07 MB
    uint16_t* ring    = (uint16_t*)alloc((size_t)R_RING * 6 * NB * NH * 2); // 12.58 MB
    int*      produced= (int*)alloc((size_t)6 * NT * 32 * 4);             // 0.19 MB
    int*      consumed= (int*)alloc((size_t)6 * NT * 32 * 4);             // 0.19 MB
    // total ~52.7 MB

    if (ws_size < off) {
        k_sentinel<<<4, 256, 0, stream>>>(out);
        return;
    }

    auto cvt = [&](const float* s, uint16_t* dmem, int n) {
        int n4 = n / 4;
        k_cvt<<<(n4 + 255) / 256, 256, 0, stream>>>(s, dmem, n4);
    };
    cvt(wih0, wih0_bf, 196608);
    cvt(wihL, wihL_bf, 1572864);
    cvt(whh, whh_bf, 1179648);
    cvt(la_w1, law1_bf, 73728);
    cvt(sa_w1, saw1_bf, 32768);
    // zero produced+consumed (contiguous, 98304 ints = 24576 float4)
    k_zero<<<96, 256, 0, stream>>>((float*)produced, 24576);

    k_encoder<<<dim3(256, 4), 256, 0, stream>>>(x, enc_w, enc_b, enc_bf);

    k_scan<<<256, BTH, 0, stream>>>(enc_bf, wih0_bf, wihL_bf, whh_bf,
                                    bih, bhh, law1_bf, la_b1, la_w2, la_b2,
                                    saw1_bf, sa_b1, sa_w2, sa_b2,
                                    ln_g, ln_b, fc_w, fc_b,
                                    ring, produced, consumed, out);
}

// Round 7
// 7516.627 us; speedup vs baseline: 18.4594x; 1.2263x over previous
//
#include <hip/hip_runtime.h>
#include <stdint.h>

// ---------------------------------------------------------------------------
// GRUClassifier round 6: LDS-resident weights + e-split stage pipeline.
// B=512, IS=128, T=256, H=256, L=3 bi-dir (both dirs forward in time).
// Round-5 finding: per-CU L2 weight re-streaming (1.15 MB/step/block) was the
// wall (36 us/step, MfmaUtil 3.4%). Fix: split each GRU stage into 8 e-slices
// x 4 batch-tiles (128 rows x 32 e-cols); per-block weights ~150 KB live in
// LDS, loaded ONCE. A-operands (h) read from a global ring with batched
// sc0/sc1 loads into registers. 224 blocks, all resident (1/CU, LDS-bound).
// Handoff: write-through ring stores + relaxed flags (validated round 5).
// Numerics (validated round 2): bf16 MFMA inputs, fp32 hidden carry.
// ---------------------------------------------------------------------------

typedef short short8 __attribute__((ext_vector_type(8)));
typedef float floatx4 __attribute__((ext_vector_type(4)));
typedef int intx4 __attribute__((ext_vector_type(4)));
typedef unsigned long long u64;

#define NB 512
#define NT 256
#define NH 256
#define NG 768
#define R_RING 8
#define RSLOT (6 * NB * NH)          // u16 elems per ring slot
#define BTH 512

__device__ __forceinline__ float bf2f(uint16_t v) {
    uint32_t u = ((uint32_t)v) << 16;
    float f;
    __builtin_memcpy(&f, &u, 4);
    return f;
}
__device__ __forceinline__ uint16_t f2bf(float f) {
    uint32_t u;
    __builtin_memcpy(&u, &f, 4);
    uint32_t r = (u + 0x7FFFu + ((u >> 16) & 1u)) >> 16;
    return (uint16_t)r;
}
__device__ __forceinline__ u64 pack4bf(float4 v) {
    u64 a = f2bf(v.x), b = f2bf(v.y), c = f2bf(v.z), d = f2bf(v.w);
    return a | (b << 16) | (c << 32) | (d << 48);
}
__device__ __forceinline__ float sigmoidf_(float x) { return 1.f / (1.f + expf(-x)); }
__device__ __forceinline__ float geluf_(float x) { return 0.5f * x * (1.f + erff(x * 0.70710678118f)); }
__device__ __forceinline__ short8 as_s8(intx4 v) { short8 r; __builtin_memcpy(&r, &v, 16); return r; }

// write-through 16B store: data to coherence point, no dirty L2 line
__device__ __forceinline__ void st_coh16(void* p, intx4 v) {
    asm volatile("global_store_dwordx4 %0, %1, off sc0 sc1"
                 :: "v"(p), "v"(v) : "memory");
}

// ---- batched coherent sequential-fragment loads (offsets kc*64 B) ---------
__device__ __forceinline__ void ld_seq8(const uint16_t* b, intx4* v) {
    asm volatile(
        "global_load_dwordx4 %0, %8, off sc0 sc1\n\t"
        "global_load_dwordx4 %1, %8, off offset:64 sc0 sc1\n\t"
        "global_load_dwordx4 %2, %8, off offset:128 sc0 sc1\n\t"
        "global_load_dwordx4 %3, %8, off offset:192 sc0 sc1\n\t"
        "global_load_dwordx4 %4, %8, off offset:256 sc0 sc1\n\t"
        "global_load_dwordx4 %5, %8, off offset:320 sc0 sc1\n\t"
        "global_load_dwordx4 %6, %8, off offset:384 sc0 sc1\n\t"
        "global_load_dwordx4 %7, %8, off offset:448 sc0 sc1\n\t"
        "s_waitcnt vmcnt(0)"
        : "=&v"(v[0]), "=&v"(v[1]), "=&v"(v[2]), "=&v"(v[3]),
          "=&v"(v[4]), "=&v"(v[5]), "=&v"(v[6]), "=&v"(v[7])
        : "v"(b) : "memory");
}
__device__ __forceinline__ void ld_seq16(const uint16_t* b0, const uint16_t* b1, intx4* v) {
    asm volatile(
        "global_load_dwordx4 %0, %16, off sc0 sc1\n\t"
        "global_load_dwordx4 %1, %16, off offset:64 sc0 sc1\n\t"
        "global_load_dwordx4 %2, %16, off offset:128 sc0 sc1\n\t"
        "global_load_dwordx4 %3, %16, off offset:192 sc0 sc1\n\t"
        "global_load_dwordx4 %4, %16, off offset:256 sc0 sc1\n\t"
        "global_load_dwordx4 %5, %16, off offset:320 sc0 sc1\n\t"
        "global_load_dwordx4 %6, %16, off offset:384 sc0 sc1\n\t"
        "global_load_dwordx4 %7, %16, off offset:448 sc0 sc1\n\t"
        "global_load_dwordx4 %8, %17, off sc0 sc1\n\t"
        "global_load_dwordx4 %9, %17, off offset:64 sc0 sc1\n\t"
        "global_load_dwordx4 %10, %17, off offset:128 sc0 sc1\n\t"
        "global_load_dwordx4 %11, %17, off offset:192 sc0 sc1\n\t"
        "global_load_dwordx4 %12, %17, off offset:256 sc0 sc1\n\t"
        "global_load_dwordx4 %13, %17, off offset:320 sc0 sc1\n\t"
        "global_load_dwordx4 %14, %17, off offset:384 sc0 sc1\n\t"
        "global_load_dwordx4 %15, %17, off offset:448 sc0 sc1\n\t"
        "s_waitcnt vmcnt(0)"
        : "=&v"(v[0]), "=&v"(v[1]), "=&v"(v[2]), "=&v"(v[3]),
          "=&v"(v[4]), "=&v"(v[5]), "=&v"(v[6]), "=&v"(v[7]),
          "=&v"(v[8]), "=&v"(v[9]), "=&v"(v[10]), "=&v"(v[11]),
          "=&v"(v[12]), "=&v"(v[13]), "=&v"(v[14]), "=&v"(v[15])
        : "v"(b0), "v"(b1) : "memory");
}
__device__ __forceinline__ void ld_seq24(const uint16_t* bg, const uint16_t* b0,
                                         const uint16_t* b1, intx4* v) {
    asm volatile(
        "global_load_dwordx4 %0, %24, off sc0 sc1\n\t"
        "global_load_dwordx4 %1, %24, off offset:64 sc0 sc1\n\t"
        "global_load_dwordx4 %2, %24, off offset:128 sc0 sc1\n\t"
        "global_load_dwordx4 %3, %24, off offset:192 sc0 sc1\n\t"
        "global_load_dwordx4 %4, %24, off offset:256 sc0 sc1\n\t"
        "global_load_dwordx4 %5, %24, off offset:320 sc0 sc1\n\t"
        "global_load_dwordx4 %6, %24, off offset:384 sc0 sc1\n\t"
        "global_load_dwordx4 %7, %24, off offset:448 sc0 sc1\n\t"
        "global_load_dwordx4 %8, %25, off sc0 sc1\n\t"
        "global_load_dwordx4 %9, %25, off offset:64 sc0 sc1\n\t"
        "global_load_dwordx4 %10, %25, off offset:128 sc0 sc1\n\t"
        "global_load_dwordx4 %11, %25, off offset:192 sc0 sc1\n\t"
        "global_load_dwordx4 %12, %25, off offset:256 sc0 sc1\n\t"
        "global_load_dwordx4 %13, %25, off offset:320 sc0 sc1\n\t"
        "global_load_dwordx4 %14, %25, off offset:384 sc0 sc1\n\t"
        "global_load_dwordx4 %15, %25, off offset:448 sc0 sc1\n\t"
        "global_load_dwordx4 %16, %26, off sc0 sc1\n\t"
        "global_load_dwordx4 %17, %26, off offset:64 sc0 sc1\n\t"
        "global_load_dwordx4 %18, %26, off offset:128 sc0 sc1\n\t"
        "global_load_dwordx4 %19, %26, off offset:192 sc0 sc1\n\t"
        "global_load_dwordx4 %20, %26, off offset:256 sc0 sc1\n\t"
        "global_load_dwordx4 %21, %26, off offset:320 sc0 sc1\n\t"
        "global_load_dwordx4 %22, %26, off offset:384 sc0 sc1\n\t"
        "global_load_dwordx4 %23, %26, off offset:448 sc0 sc1\n\t"
        "s_waitcnt vmcnt(0)"
        : "=&v"(v[0]), "=&v"(v[1]), "=&v"(v[2]), "=&v"(v[3]),
          "=&v"(v[4]), "=&v"(v[5]), "=&v"(v[6]), "=&v"(v[7]),
          "=&v"(v[8]), "=&v"(v[9]), "=&v"(v[10]), "=&v"(v[11]),
          "=&v"(v[12]), "=&v"(v[13]), "=&v"(v[14]), "=&v"(v[15]),
          "=&v"(v[16]), "=&v"(v[17]), "=&v"(v[18]), "=&v"(v[19]),
          "=&v"(v[20]), "=&v"(v[21]), "=&v"(v[22]), "=&v"(v[23])
        : "v"(bg), "v"(b0), "v"(b1) : "memory");
}
// 6 scattered coherent loads (attention staging)
__device__ __forceinline__ void ld_sc6(
    const uint16_t* p0, const uint16_t* p1, const uint16_t* p2,
    const uint16_t* p3, const uint16_t* p4, const uint16_t* p5, intx4* v) {
    asm volatile(
        "global_load_dwordx4 %0, %6, off sc0 sc1\n\t"
        "global_load_dwordx4 %1, %7, off sc0 sc1\n\t"
        "global_load_dwordx4 %2, %8, off sc0 sc1\n\t"
        "global_load_dwordx4 %3, %9, off sc0 sc1\n\t"
        "global_load_dwordx4 %4, %10, off sc0 sc1\n\t"
        "global_load_dwordx4 %5, %11, off sc0 sc1\n\t"
        "s_waitcnt vmcnt(0)"
        : "=&v"(v[0]), "=&v"(v[1]), "=&v"(v[2]), "=&v"(v[3]), "=&v"(v[4]), "=&v"(v[5])
        : "v"(p0), "v"(p1), "v"(p2), "v"(p3), "v"(p4), "v"(p5)
        : "memory");
}

#define PIDX(s, t, bt) ((((s) * NT) + (t)) * 4 + (bt))

// ---------------- small utility kernels ------------------------------------
__global__ void k_cvt(const float* __restrict__ src, uint16_t* __restrict__ dst, int n4) {
    int i = blockIdx.x * blockDim.x + threadIdx.x;
    if (i < n4) {
        float4 v = ((const float4*)src)[i];
        ushort4 o;
        o.x = f2bf(v.x); o.y = f2bf(v.y); o.z = f2bf(v.z); o.w = f2bf(v.w);
        ((ushort4*)dst)[i] = o;
    }
}
__global__ void k_zero(float* __restrict__ p, int n4) {
    int i = blockIdx.x * blockDim.x + threadIdx.x;
    if (i < n4) ((float4*)p)[i] = make_float4(0.f, 0.f, 0.f, 0.f);
}
__global__ void k_sentinel(float* __restrict__ out) {
    int i = blockIdx.x * blockDim.x + threadIdx.x;
    if (i < 1024) out[i] = -99999.0f;
}

// ---------------- encoder: encoded = mish(x @ enc_w^T + enc_b), bf16 out ----
__global__ __launch_bounds__(256) void k_encoder(
    const float* __restrict__ x, const float* __restrict__ enc_w,
    const float* __restrict__ enc_b, uint16_t* __restrict__ enc_out) {
    const int tid = threadIdx.x;
    const int lane = tid & 63, wid = tid >> 6;
    const int q = lane >> 4, l15 = lane & 15;
    const int wm = wid >> 1, wj = wid & 1;
    const int j0 = blockIdx.x * 128, b0 = blockIdx.y * 128;

    __shared__ uint16_t a_s[128 * 72];
    __shared__ uint16_t w_s[128 * 72];

#pragma unroll
    for (int jj = 0; jj < 8; ++jj) {
        int u = tid + jj * 256;
        int r = u >> 4, c4 = (u & 15) * 4;
        float4 va = *(const float4*)&x[(size_t)(b0 + r) * 64 + c4];
        float4 vw = *(const float4*)&enc_w[(size_t)(j0 + r) * 64 + c4];
        *(u64*)&a_s[r * 72 + c4] = pack4bf(va);
        *(u64*)&w_s[r * 72 + c4] = pack4bf(vw);
    }
    __syncthreads();

    floatx4 acc[4][4];
#pragma unroll
    for (int mi = 0; mi < 4; ++mi)
#pragma unroll
        for (int nf = 0; nf < 4; ++nf) acc[mi][nf] = (floatx4){0.f, 0.f, 0.f, 0.f};

#pragma unroll
    for (int kc = 0; kc < 2; ++kc) {
        short8 af[4], bfg[4];
#pragma unroll
        for (int mi = 0; mi < 4; ++mi)
            af[mi] = *(const short8*)&a_s[(wm * 64 + mi * 16 + l15) * 72 + kc * 32 + q * 8];
#pragma unroll
        for (int nf = 0; nf < 4; ++nf)
            bfg[nf] = *(const short8*)&w_s[(wj * 64 + nf * 16 + l15) * 72 + kc * 32 + q * 8];
#pragma unroll
        for (int mi = 0; mi < 4; ++mi)
#pragma unroll
            for (int nf = 0; nf < 4; ++nf)
                acc[mi][nf] = __builtin_amdgcn_mfma_f32_16x16x32_bf16(af[mi], bfg[nf], acc[mi][nf], 0, 0, 0);
    }

#pragma unroll
    for (int nf = 0; nf < 4; ++nf) {
        int j = j0 + wj * 64 + nf * 16 + l15;
        float eb = enc_b[j];
#pragma unroll
        for (int mi = 0; mi < 4; ++mi)
#pragma unroll
            for (int r = 0; r < 4; ++r) {
                int b = b0 + wm * 64 + mi * 16 + q * 4 + r;
                float v = acc[mi][nf][r] + eb;
                float sp = (v > 20.f) ? v : log1pf(expf(v));
                float m = v * tanhf(sp);
                enc_out[(size_t)b * 32768 + j] = f2bf(m);
            }
    }
}

// ---------------- shared memory layouts ------------------------------------
struct SGru {
    uint16_t wgi[96 * 520];   // [3g*32r][K(+8 pad)]  (l=0: stride 136 region)
    uint16_t wgh[96 * 264];   // [3g*32r][256+8]
    uint16_t h_out[128 * 32]; // publish staging
};
struct SAtt {
    uint16_t hbf[6 * 16 * 264];
    float laP[3][3][16];
    float saT[4][16][17];
    float s_s[16], lg_s[16];
};
union SMem { SGru g; SAtt a; };

// ---------------- pipelined scan kernel ------------------------------------
// grid 224 x 512 thr.
//  b<192: GRU block: sd=b>>5 (stage l*2+d), es=(b&31)>>2 (8 e-slices of 32),
//         bt=b&3 (4 batch tiles of 128 rows).
//  b>=192: attention block ab=b-192 (32 blocks of 16 rows).
__global__ __launch_bounds__(BTH) void k_scan(
    const uint16_t* __restrict__ enc_bf,
    const uint16_t* __restrict__ wih0_bf, const uint16_t* __restrict__ wihL_bf,
    const uint16_t* __restrict__ whh_bf,
    const float* __restrict__ bih, const float* __restrict__ bhh,
    const uint16_t* __restrict__ law1_bf, const float* __restrict__ la_b1,
    const float* __restrict__ la_w2, const float* __restrict__ la_b2,
    const uint16_t* __restrict__ saw1_bf, const float* __restrict__ sa_b1,
    const float* __restrict__ sa_w2, const float* __restrict__ sa_b2,
    const float* __restrict__ ln_g, const float* __restrict__ ln_b,
    const float* __restrict__ fc_w, const float* __restrict__ fc_b,
    uint16_t* __restrict__ ring, int* produced, int* consumed,
    float* __restrict__ out) {
    const int blk = blockIdx.x;
    const int tid = threadIdx.x;
    const int w = tid >> 6;
    const int lane = tid & 63;
    const int q = lane >> 4, l15 = lane & 15;

    __shared__ SMem sm;

    if (blk < 192) {
        // =================== GRU stage block ===============================
        const int sd = blk >> 5;
        const int l = sd >> 1, dd = sd & 1;
        const int rem = blk & 31;
        const int es = rem >> 2;
        const int bt = rem & 3;
        const int row0 = bt * 128;
        const int Kgi = (l == 0) ? 128 : 512;
        const int ksh = (l == 0) ? 7 : 9;
        const int strgi = Kgi + 8;
        const uint16_t* wih = (l == 0) ? wih0_bf + (size_t)dd * NG * 128
                                       : wihL_bf + (size_t)((l - 1) * 2 + dd) * NG * 512;
        const uint16_t* whhp = whh_bf + (size_t)sd * NG * 256;
        const int ncons = (l < 2) ? 32 : 16;

        // ---- load weights into LDS (once) ----
        for (int flat = tid * 8; flat < 96 * Kgi; flat += BTH * 8) {
            int r = flat >> ksh, c = flat & (Kgi - 1);
            int g = r >> 5, rr = r & 31;
            int srow = g * 256 + es * 32 + rr;
            *(intx4*)&sm.g.wgi[r * strgi + c] = *(const intx4*)&wih[(size_t)srow * Kgi + c];
        }
        for (int flat = tid * 8; flat < 96 * 256; flat += BTH * 8) {
            int r = flat >> 8, c = flat & 255;
            int g = r >> 5, rr = r & 31;
            int srow = g * 256 + es * 32 + rr;
            *(intx4*)&sm.g.wgh[r * 264 + c] = *(const intx4*)&whhp[(size_t)srow * 256 + c];
        }
        // biases (per lane: col = es*32 + sub*16 + l15)
        float bRs[2], bZs[2], bNs[2], bHNs[2];
        {
            int ba = sd * NG;
#pragma unroll
            for (int sub = 0; sub < 2; ++sub) {
                int e = es * 32 + sub * 16 + l15;
                bRs[sub] = bih[ba + e] + bhh[ba + e];
                bZs[sub] = bih[ba + 256 + e] + bhh[ba + 256 + e];
                bNs[sub] = bih[ba + 512 + e];
                bHNs[sub] = bhh[ba + 512 + e];
            }
        }
        // B-fragment LDS offsets (precomputed)
        int wofs_gi[2][3], wofs_gh[2][3];
#pragma unroll
        for (int sub = 0; sub < 2; ++sub)
#pragma unroll
            for (int g = 0; g < 3; ++g) {
                wofs_gi[sub][g] = (g * 32 + sub * 16 + l15) * strgi + q * 8;
                wofs_gh[sub][g] = (g * 32 + sub * 16 + l15) * 264 + q * 8;
            }
        float hreg[2][4];
#pragma unroll
        for (int sub = 0; sub < 2; ++sub)
#pragma unroll
            for (int r = 0; r < 4; ++r) hreg[sub][r] = 0.f;
        __syncthreads();

        const int myrow = row0 + w * 16 + l15;

        for (int t = 0; t < NT; ++t) {
            // ---- waits (thread 0): back-pressure, own t-1, upstream t ----
            if (tid == 0) {
                if (t >= R_RING) {
                    const int* cp = &consumed[PIDX(sd, t - R_RING, bt)];
                    while (__hip_atomic_load(cp, __ATOMIC_RELAXED, __HIP_MEMORY_SCOPE_AGENT) < ncons)
                        __builtin_amdgcn_s_sleep(1);
                }
                if (t >= 1) {
                    const int* sp = &produced[PIDX(sd, t - 1, bt)];
                    while (__hip_atomic_load(sp, __ATOMIC_RELAXED, __HIP_MEMORY_SCOPE_AGENT) < 8)
                        __builtin_amdgcn_s_sleep(1);
                }
                if (l > 0) {
                    const int* p0 = &produced[PIDX(2 * (l - 1), t, bt)];
                    const int* p1 = &produced[PIDX(2 * (l - 1) + 1, t, bt)];
                    while (__hip_atomic_load(p0, __ATOMIC_RELAXED, __HIP_MEMORY_SCOPE_AGENT) < 8)
                        __builtin_amdgcn_s_sleep(1);
                    while (__hip_atomic_load(p1, __ATOMIC_RELAXED, __HIP_MEMORY_SCOPE_AGENT) < 8)
                        __builtin_amdgcn_s_sleep(1);
                }
            }
            __syncthreads();

            // ---- A-fragment loads: av[0..7]=gh(t-1), av[8..23]=gi(t) ----
            intx4 av[24];
            const uint16_t* ghb =
                ring + (size_t)((t - 1) & 7) * RSLOT + ((size_t)sd * NB + myrow) * NH + q * 8;
            if (l > 0) {
                const uint16_t* gib0 =
                    ring + (size_t)(t & 7) * RSLOT + ((size_t)(2 * l - 2) * NB + myrow) * NH + q * 8;
                const uint16_t* gib1 =
                    ring + (size_t)(t & 7) * RSLOT + ((size_t)(2 * l - 1) * NB + myrow) * NH + q * 8;
                if (t > 0) {
                    ld_seq24(ghb, gib0, gib1, av);
                } else {
                    ld_seq16(gib0, gib1, av + 8);
#pragma unroll
                    for (int i = 0; i < 8; ++i) av[i] = (intx4){0, 0, 0, 0};
                }
            } else {
                if (t > 0) ld_seq8(ghb, av);
                else {
#pragma unroll
                    for (int i = 0; i < 8; ++i) av[i] = (intx4){0, 0, 0, 0};
                }
                const uint16_t* eb = enc_bf + ((size_t)myrow << 15) + t * 128 + q * 8;
#pragma unroll
                for (int kc = 0; kc < 4; ++kc)
                    __builtin_memcpy(&av[8 + kc], eb + kc * 32, 16);
            }

            // ---- MFMA ----
            floatx4 aR[2], aZ[2], aNi[2], aNh[2];
#pragma unroll
            for (int sub = 0; sub < 2; ++sub) {
                floatx4 z = (floatx4){0.f, 0.f, 0.f, 0.f};
                aR[sub] = z; aZ[sub] = z; aNi[sub] = z; aNh[sub] = z;
            }
            const int nkc = Kgi >> 5;
            for (int kc = 0; kc < nkc; ++kc) {
                short8 afr = as_s8(av[8 + kc]);
#pragma unroll
                for (int sub = 0; sub < 2; ++sub) {
                    short8 b0f = *(const short8*)&sm.g.wgi[wofs_gi[sub][0] + kc * 32];
                    short8 b1f = *(const short8*)&sm.g.wgi[wofs_gi[sub][1] + kc * 32];
                    short8 b2f = *(const short8*)&sm.g.wgi[wofs_gi[sub][2] + kc * 32];
                    aR[sub]  = __builtin_amdgcn_mfma_f32_16x16x32_bf16(afr, b0f, aR[sub], 0, 0, 0);
                    aZ[sub]  = __builtin_amdgcn_mfma_f32_16x16x32_bf16(afr, b1f, aZ[sub], 0, 0, 0);
                    aNi[sub] = __builtin_amdgcn_mfma_f32_16x16x32_bf16(afr, b2f, aNi[sub], 0, 0, 0);
                }
            }
#pragma unroll 2
            for (int kc = 0; kc < 8; ++kc) {
                short8 afr = as_s8(av[kc]);
#pragma unroll
                for (int sub = 0; sub < 2; ++sub) {
                    short8 b0f = *(const short8*)&sm.g.wgh[wofs_gh[sub][0] + kc * 32];
                    short8 b1f = *(const short8*)&sm.g.wgh[wofs_gh[sub][1] + kc * 32];
                    short8 b2f = *(const short8*)&sm.g.wgh[wofs_gh[sub][2] + kc * 32];
                    aR[sub]  = __builtin_amdgcn_mfma_f32_16x16x32_bf16(afr, b0f, aR[sub], 0, 0, 0);
                    aZ[sub]  = __builtin_amdgcn_mfma_f32_16x16x32_bf16(afr, b1f, aZ[sub], 0, 0, 0);
                    aNh[sub] = __builtin_amdgcn_mfma_f32_16x16x32_bf16(afr, b2f, aNh[sub], 0, 0, 0);
                }
            }

            // ---- epilogue: gates + state update -> h_out ----
#pragma unroll
            for (int sub = 0; sub < 2; ++sub) {
#pragma unroll
                for (int r = 0; r < 4; ++r) {
                    float rr = sigmoidf_(aR[sub][r] + bRs[sub]);
                    float zz = sigmoidf_(aZ[sub][r] + bZs[sub]);
                    float nn = tanhf(aNi[sub][r] + bNs[sub] + rr * (aNh[sub][r] + bHNs[sub]));
                    float hn = (1.f - zz) * nn + zz * hreg[sub][r];
                    hreg[sub][r] = hn;
                    sm.g.h_out[(w * 16 + q * 4 + r) * 32 + sub * 16 + l15] = f2bf(hn);
                }
            }
            __syncthreads();
            // ---- publish slice (write-through) ----
            {
                int r = tid >> 2, part = tid & 3;
                st_coh16(ring + (size_t)(t & 7) * RSLOT +
                             ((size_t)sd * NB + row0 + r) * NH + es * 32 + part * 8,
                         *(const intx4*)&sm.g.h_out[r * 32 + part * 8]);
            }
            __syncthreads();   // all waves' stores drained (per-wave vmcnt before barrier)
            if (tid == 0) {
                asm volatile("s_waitcnt vmcnt(0)" ::: "memory");
                __hip_atomic_fetch_add(&produced[PIDX(sd, t, bt)], 1,
                                       __ATOMIC_RELAXED, __HIP_MEMORY_SCOPE_AGENT);
                if (l > 0) {
                    __hip_atomic_fetch_add(&consumed[PIDX(2 * l - 2, t, bt)], 1,
                                           __ATOMIC_RELAXED, __HIP_MEMORY_SCOPE_AGENT);
                    __hip_atomic_fetch_add(&consumed[PIDX(2 * l - 1, t, bt)], 1,
                                           __ATOMIC_RELAXED, __HIP_MEMORY_SCOPE_AGENT);
                }
                if (t >= 1)
                    __hip_atomic_fetch_add(&consumed[PIDX(sd, t - 1, bt)], 1,
                                           __ATOMIC_RELAXED, __HIP_MEMORY_SCOPE_AGENT);
            }
        }
        return;
    }

    // =================== attention block (16 rows) =========================
    const int ab = blk - 192;
    const int b0 = ab * 16;
    const int bt = ab >> 3;
    const int lA = w / 3, nfA = w % 3;
    const float b1A = la_b1[lA * 48 + nfA * 16 + l15];
    const float w2A = la_w2[lA * 48 + nfA * 16 + l15];
    float b1B = 0.f, w2B = 0.f;
    if (w == 0) { b1B = la_b1[2 * 48 + 2 * 16 + l15]; w2B = la_w2[2 * 48 + 2 * 16 + l15]; }
    float nacc[16];
#pragma unroll
    for (int j = 0; j < 16; ++j) nacc[j] = 0.f;
    float m_r = -1e30f, d_r = 0.f;

    for (int t = 0; t < NT; ++t) {
        if (tid == 0) {
            // produced[4],[5]==8 transitively implies states 0..3 complete
            const int* p4 = &produced[PIDX(4, t, bt)];
            const int* p5 = &produced[PIDX(5, t, bt)];
            while (__hip_atomic_load(p4, __ATOMIC_RELAXED, __HIP_MEMORY_SCOPE_AGENT) < 8)
                __builtin_amdgcn_s_sleep(1);
            while (__hip_atomic_load(p5, __ATOMIC_RELAXED, __HIP_MEMORY_SCOPE_AGENT) < 8)
                __builtin_amdgcn_s_sleep(1);
        }
        __syncthreads();
        // ---- stage all 6 states into hbf (6 batched coherent loads) ----
        {
            const uint16_t* base = ring + (size_t)(t & 7) * RSLOT;
            const uint16_t* ps[6];
            int di[6];
#pragma unroll
            for (int i = 0; i < 6; ++i) {
                int f = i * 512 + tid;
                int s = f >> 9, r = (f >> 5) & 15, g = f & 31;
                ps[i] = base + ((size_t)s * NB + b0 + r) * NH + g * 8;
                di[i] = (s * 16 + r) * 264 + g * 8;
            }
            intx4 v[6];
            ld_sc6(ps[0], ps[1], ps[2], ps[3], ps[4], ps[5], v);
#pragma unroll
            for (int i = 0; i < 6; ++i) *(intx4*)&sm.a.hbf[di[i]] = v[i];
        }
        __syncthreads();
        if (tid == 0) {
#pragma unroll
            for (int s = 0; s < 6; ++s)
                __hip_atomic_fetch_add(&consumed[PIDX(s, t, bt)], 1,
                                       __ATOMIC_RELAXED, __HIP_MEMORY_SCOPE_AGENT);
        }
        // ---- job A: la(lA, nfA) ----
        {
            floatx4 ac = (floatx4){0.f, 0.f, 0.f, 0.f};
#pragma unroll 2
            for (int kc = 0; kc < 512; kc += 32) {
                int k = kc + q * 8;
                int s = 2 * lA + (k >= 256 ? 1 : 0);
                short8 afr = *(const short8*)&sm.a.hbf[(s * 16 + l15) * 264 + (k & 255)];
                const uint16_t* wr = law1_bf + (size_t)(lA * 48 + nfA * 16 + l15) * 512 + k;
                ac = __builtin_amdgcn_mfma_f32_16x16x32_bf16(afr, *(const short8*)wr, ac, 0, 0, 0);
            }
#pragma unroll
            for (int r = 0; r < 4; ++r) {
                float v = geluf_(ac[r] + b1A) * w2A;
                v += __shfl_xor(v, 1, 64);
                v += __shfl_xor(v, 2, 64);
                v += __shfl_xor(v, 4, 64);
                v += __shfl_xor(v, 8, 64);
                if (l15 == 0) sm.a.laP[lA][nfA][q * 4 + r] = v;
            }
        }
        // ---- job B ----
        if (w == 0) {           // la(2,2)
            floatx4 ac = (floatx4){0.f, 0.f, 0.f, 0.f};
#pragma unroll 2
            for (int kc = 0; kc < 512; kc += 32) {
                int k = kc + q * 8;
                int s = 4 + (k >= 256 ? 1 : 0);
                short8 afr = *(const short8*)&sm.a.hbf[(s * 16 + l15) * 264 + (k & 255)];
                const uint16_t* wr = law1_bf + (size_t)(2 * 48 + 2 * 16 + l15) * 512 + k;
                ac = __builtin_amdgcn_mfma_f32_16x16x32_bf16(afr, *(const short8*)wr, ac, 0, 0, 0);
            }
#pragma unroll
            for (int r = 0; r < 4; ++r) {
                float v = geluf_(ac[r] + b1B) * w2B;
                v += __shfl_xor(v, 1, 64);
                v += __shfl_xor(v, 2, 64);
                v += __shfl_xor(v, 4, 64);
                v += __shfl_xor(v, 8, 64);
                if (l15 == 0) sm.a.laP[2][2][q * 4 + r] = v;
            }
        } else if (w <= 4) {    // sa tile nf = w-1 (raw pre-acts)
            int nf = w - 1;
            floatx4 ac = (floatx4){0.f, 0.f, 0.f, 0.f};
#pragma unroll 2
            for (int kc = 0; kc < 512; kc += 32) {
                int k = kc + q * 8;
                int s = 4 + (k >= 256 ? 1 : 0);
                short8 afr = *(const short8*)&sm.a.hbf[(s * 16 + l15) * 264 + (k & 255)];
                const uint16_t* wr = saw1_bf + (size_t)(nf * 16 + l15) * 512 + k;
                ac = __builtin_amdgcn_mfma_f32_16x16x32_bf16(afr, *(const short8*)wr, ac, 0, 0, 0);
            }
#pragma unroll
            for (int r = 0; r < 4; ++r) sm.a.saT[nf][q * 4 + r][l15] = ac[r];
        }
        __syncthreads();
        // ---- combine: s and logit per row (wave 0) ----
        if (w == 0) {
            int row = l15;
            float sv = 0.f;
#pragma unroll
            for (int l = 0; l < 3; ++l)
                sv += sigmoidf_(sm.a.laP[l][0][row] + sm.a.laP[l][1][row] +
                                sm.a.laP[l][2][row] + la_b2[l]);
            float a2 = 0.f;
#pragma unroll
            for (int i = 0; i < 16; ++i) {
                int c = q * 16 + i;
                float pre = sv * sm.a.saT[q][row][i] + sa_b1[c];
                a2 += pre * sigmoidf_(pre) * sa_w2[c];
            }
            a2 += __shfl_xor(a2, 16, 64);
            a2 += __shfl_xor(a2, 32, 64);
            if (q == 0 && lane < 16) { sm.a.s_s[row] = sv; sm.a.lg_s[row] = a2 + sa_b2[0]; }
        }
        __syncthreads();
        // ---- online softmax update (wave w owns rows 2w, 2w+1) ----
        {
            int myrow = 2 * w + (lane >> 5);
            int ci = lane & 31;
            float lg = sm.a.lg_s[myrow], sv = sm.a.s_s[myrow];
            float mn = fmaxf(m_r, lg);
            float cs = expf(m_r - mn);
            float e = expf(lg - mn);
            m_r = mn;
            d_r = d_r * cs + e;
            float wf = e * sv;
            int st = 4 + (ci >> 4);
            int c0 = (ci & 15) * 16;
            const uint16_t* hp = &sm.a.hbf[(size_t)(st * 16 + myrow) * 264 + c0];
            short8 o0 = *(const short8*)hp;
            short8 o1 = *(const short8*)(hp + 8);
#pragma unroll
            for (int j = 0; j < 8; ++j) {
                nacc[j]     = nacc[j] * cs + wf * bf2f((uint16_t)o0[j]);
                nacc[8 + j] = nacc[8 + j] * cs + wf * bf2f((uint16_t)o1[j]);
            }
        }
        __syncthreads();   // protect hbf/s_s before next step's staging
    }

    // ---- finalize: context -> LN -> FC ----
    {
        int myrow = 2 * w + (lane >> 5);
        int ci = lane & 31;
        float dinv = 1.f / d_r;
        float cv[16];
        float s1 = 0.f, s2 = 0.f;
#pragma unroll
        for (int j = 0; j < 16; ++j) {
            cv[j] = nacc[j] * dinv;
            s1 += cv[j];
            s2 += cv[j] * cv[j];
        }
        s1 += __shfl_xor(s1, 1, 64);  s2 += __shfl_xor(s2, 1, 64);
        s1 += __shfl_xor(s1, 2, 64);  s2 += __shfl_xor(s2, 2, 64);
        s1 += __shfl_xor(s1, 4, 64);  s2 += __shfl_xor(s2, 4, 64);
        s1 += __shfl_xor(s1, 8, 64);  s2 += __shfl_xor(s2, 8, 64);
        s1 += __shfl_xor(s1, 16, 64); s2 += __shfl_xor(s2, 16, 64);
        float mean = s1 / 512.f;
        float var = s2 / 512.f - mean * mean;
        float rstd = rsqrtf(var + 1e-5f);
        float p0 = 0.f, p1 = 0.f;
#pragma unroll
        for (int j = 0; j < 16; ++j) {
            int g = ci * 16 + j;
            float nv = (cv[j] - mean) * rstd * ln_g[g] + ln_b[g];
            p0 += nv * fc_w[g];
            p1 += nv * fc_w[512 + g];
        }
        p0 += __shfl_xor(p0, 1, 64);  p1 += __shfl_xor(p1, 1, 64);
        p0 += __shfl_xor(p0, 2, 64);  p1 += __shfl_xor(p1, 2, 64);
        p0 += __shfl_xor(p0, 4, 64);  p1 += __shfl_xor(p1, 4, 64);
        p0 += __shfl_xor(p0, 8, 64);  p1 += __shfl_xor(p1, 8, 64);
        p0 += __shfl_xor(p0, 16, 64); p1 += __shfl_xor(p1, 16, 64);
        if ((lane & 31) == 0) {
            out[(b0 + myrow) * 2 + 0] = p0 + fc_b[0];
            out[(b0 + myrow) * 2 + 1] = p1 + fc_b[1];
        }
    }
}

// ---------------------------------------------------------------------------
extern "C" void kernel_launch(void* const* d_in, const int* in_sizes, int n_in,
                              void* d_out, int out_size, void* d_ws, size_t ws_size,
                              hipStream_t stream) {
    const float* x     = (const float*)d_in[0];
    const float* enc_w = (const float*)d_in[1];
    const float* enc_b = (const float*)d_in[2];
    const float* wih0  = (const float*)d_in[3];
    const float* wihL  = (const float*)d_in[4];
    const float* whh   = (const float*)d_in[5];
    const float* bih   = (const float*)d_in[6];
    const float* bhh   = (const float*)d_in[7];
    const float* la_w1 = (const float*)d_in[8];
    const float* la_b1 = (const float*)d_in[9];
    const float* la_w2 = (const float*)d_in[10];
    const float* la_b2 = (const float*)d_in[11];
    const float* sa_w1 = (const float*)d_in[12];
    const float* sa_b1 = (const float*)d_in[13];
    const float* sa_w2 = (const float*)d_in[14];
    const float* sa_b2 = (const float*)d_in[15];
    const float* ln_g  = (const float*)d_in[16];
    const float* ln_b  = (const float*)d_in[17];
    const float* fc_w  = (const float*)d_in[18];
    const float* fc_b  = (const float*)d_in[19];
    float* out = (float*)d_out;

    uint8_t* wsb = (uint8_t*)d_ws;
    size_t off = 0;
    auto alloc = [&](size_t bytes) -> void* {
        void* p = wsb + off;
        off += (bytes + 255) & ~(size_t)255;
        return p;
    };
    uint16_t* enc_bf  = (uint16_t*)alloc((size_t)NB * 32768 * 2);          // 33.55 MB
    uint16_t* wih0_bf = (uint16_t*)alloc((size_t)2 * NG * 128 * 2);        // 0.39 MB
    uint16_t* wihL_bf = (uint16_t*)alloc((size_t)2 * 2 * NG * 512 * 2);    // 3.15 MB
    uint16_t* whh_bf  = (uint16_t*)alloc((size_t)3 * 2 * NG * 256 * 2);    // 2.36 MB
    uint16_t* law1_bf = (uint16_t*)alloc((size_t)3 * 48 * 512 * 2);        // 0.15 MB
    uint16_t* saw1_bf = (uint16_t*)alloc((size_t)64 * 512 * 2);            // 0.07 MB
    uint16_t* ring    = (uint16_t*)alloc((size_t)R_RING * RSLOT * 2);      // 12.58 MB
    int*      produced= (int*)alloc((size_t)6 * NT * 4 * 4);               // 24 KB
    int*      consumed= (int*)alloc((size_t)6 * NT * 4 * 4);               // 24 KB
    // total ~52.3 MB

    if (ws_size < off) {
        k_sentinel<<<4, 256, 0, stream>>>(out);
        return;
    }

    auto cvt = [&](const float* s, uint16_t* dmem, int n) {
        int n4 = n / 4;
        k_cvt<<<(n4 + 255) / 256, 256, 0, stream>>>(s, dmem, n4);
    };
    cvt(wih0, wih0_bf, 196608);
    cvt(wihL, wihL_bf, 1572864);
    cvt(whh, whh_bf, 1179648);
    cvt(la_w1, law1_bf, 73728);
    cvt(sa_w1, saw1_bf, 32768);
    // zero produced+consumed (contiguous: 2 * 6144 ints = 3072 float4)
    k_zero<<<12, 256, 0, stream>>>((float*)produced, 3072);

    k_encoder<<<dim3(256, 4), 256, 0, stream>>>(x, enc_w, enc_b, enc_bf);

    k_scan<<<224, BTH, 0, stream>>>(enc_bf, wih0_bf, wihL_bf, whh_bf,
                                    bih, bhh, law1_bf, la_b1, la_w2, la_b2,
                                    saw1_bf, sa_b1, sa_w2, sa_b2,
                                    ln_g, ln_b, fc_w, fc_b,
                                    ring, produced, consumed, out);
}

// Round 8
// 7241.801 us; speedup vs baseline: 19.1600x; 1.0379x over previous
//
#include <hip/hip_runtime.h>
#include <stdint.h>

// ---------------------------------------------------------------------------
// GRUClassifier round 7: LDS-resident weights + e-split pipeline, es-major
// ring layout.
// Round-6 finding: scattered 64B sc0/sc1 ring writes amplified 20x at the
// MALL/HBM (WRITE_SIZE 8.2 GB vs 0.40 GB logical); producers stall draining
// them. Fix: ring re-layout to [sd][es][row][32col] so each block's publish
// is one contiguous 8 KB burst; consumer reads via SGPR-base + loop-invariant
// VGPR offsets (plane stride 32 KB). Publish stores drain per-thread before
// the barrier (fixes a latent flag/store race).
// Architecture (validated round 6): 6 GRU stages x 8 e-slices x 4 batch
// tiles + 32 attention blocks = 224 blocks, weights in LDS, relaxed flags.
// Numerics (validated round 2): bf16 MFMA inputs, fp32 hidden carry.
// ---------------------------------------------------------------------------

typedef short short8 __attribute__((ext_vector_type(8)));
typedef float floatx4 __attribute__((ext_vector_type(4)));
typedef int intx4 __attribute__((ext_vector_type(4)));
typedef unsigned long long u64;

#define NB 512
#define NT 256
#define NH 256
#define NG 768
#define R_RING 8
#define RSLOT (6 * NB * NH)          // u16 elems per ring slot
#define BTH 512

__device__ __forceinline__ float bf2f(uint16_t v) {
    uint32_t u = ((uint32_t)v) << 16;
    float f;
    __builtin_memcpy(&f, &u, 4);
    return f;
}
__device__ __forceinline__ uint16_t f2bf(float f) {
    uint32_t u;
    __builtin_memcpy(&u, &f, 4);
    uint32_t r = (u + 0x7FFFu + ((u >> 16) & 1u)) >> 16;
    return (uint16_t)r;
}
__device__ __forceinline__ u64 pack4bf(float4 v) {
    u64 a = f2bf(v.x), b = f2bf(v.y), c = f2bf(v.z), d = f2bf(v.w);
    return a | (b << 16) | (c << 32) | (d << 48);
}
__device__ __forceinline__ float sigmoidf_(float x) { return 1.f / (1.f + expf(-x)); }
__device__ __forceinline__ float geluf_(float x) { return 0.5f * x * (1.f + erff(x * 0.70710678118f)); }
__device__ __forceinline__ short8 as_s8(intx4 v) { short8 r; __builtin_memcpy(&r, &v, 16); return r; }

// write-through 16B store + own-thread drain (so barrier implies visibility)
__device__ __forceinline__ void st_coh16_wait(void* p, intx4 v) {
    asm volatile("global_store_dwordx4 %0, %1, off sc0 sc1\n\ts_waitcnt vmcnt(0)"
                 :: "v"(p), "v"(v) : "memory");
}

// 8 coherent loads from one plane-base (SGPR) with per-lane 32-bit offsets
__device__ __forceinline__ void ld_plane8(u64 sbase,
    uint32_t o0, uint32_t o1, uint32_t o2, uint32_t o3,
    uint32_t o4, uint32_t o5, uint32_t o6, uint32_t o7, intx4* v) {
    asm volatile(
        "global_load_dwordx4 %0, %8, %16 sc0 sc1\n\t"
        "global_load_dwordx4 %1, %9, %16 sc0 sc1\n\t"
        "global_load_dwordx4 %2, %10, %16 sc0 sc1\n\t"
        "global_load_dwordx4 %3, %11, %16 sc0 sc1\n\t"
        "global_load_dwordx4 %4, %12, %16 sc0 sc1\n\t"
        "global_load_dwordx4 %5, %13, %16 sc0 sc1\n\t"
        "global_load_dwordx4 %6, %14, %16 sc0 sc1\n\t"
        "global_load_dwordx4 %7, %15, %16 sc0 sc1"
        : "=&v"(v[0]), "=&v"(v[1]), "=&v"(v[2]), "=&v"(v[3]),
          "=&v"(v[4]), "=&v"(v[5]), "=&v"(v[6]), "=&v"(v[7])
        : "v"(o0), "v"(o1), "v"(o2), "v"(o3), "v"(o4), "v"(o5), "v"(o6), "v"(o7),
          "s"(sbase)
        : "memory");
}
// drain all outstanding vmem; ties 8 values so their uses can't be hoisted
__device__ __forceinline__ void wait_vm8(intx4* v) {
    asm volatile("s_waitcnt vmcnt(0)"
                 : "+v"(v[0]), "+v"(v[1]), "+v"(v[2]), "+v"(v[3]),
                   "+v"(v[4]), "+v"(v[5]), "+v"(v[6]), "+v"(v[7])
                 :: "memory");
}
// 6 scattered coherent loads (attention staging)
__device__ __forceinline__ void ld_sc6(
    const uint16_t* p0, const uint16_t* p1, const uint16_t* p2,
    const uint16_t* p3, const uint16_t* p4, const uint16_t* p5, intx4* v) {
    asm volatile(
        "global_load_dwordx4 %0, %6, off sc0 sc1\n\t"
        "global_load_dwordx4 %1, %7, off sc0 sc1\n\t"
        "global_load_dwordx4 %2, %8, off sc0 sc1\n\t"
        "global_load_dwordx4 %3, %9, off sc0 sc1\n\t"
        "global_load_dwordx4 %4, %10, off sc0 sc1\n\t"
        "global_load_dwordx4 %5, %11, off sc0 sc1\n\t"
        "s_waitcnt vmcnt(0)"
        : "=&v"(v[0]), "=&v"(v[1]), "=&v"(v[2]), "=&v"(v[3]), "=&v"(v[4]), "=&v"(v[5])
        : "v"(p0), "v"(p1), "v"(p2), "v"(p3), "v"(p4), "v"(p5)
        : "memory");
}

#define PIDX(s, t, bt) ((((s) * NT) + (t)) * 4 + (bt))

// ---------------- small utility kernels ------------------------------------
__global__ void k_cvt(const float* __restrict__ src, uint16_t* __restrict__ dst, int n4) {
    int i = blockIdx.x * blockDim.x + threadIdx.x;
    if (i < n4) {
        float4 v = ((const float4*)src)[i];
        ushort4 o;
        o.x = f2bf(v.x); o.y = f2bf(v.y); o.z = f2bf(v.z); o.w = f2bf(v.w);
        ((ushort4*)dst)[i] = o;
    }
}
__global__ void k_zero(float* __restrict__ p, int n4) {
    int i = blockIdx.x * blockDim.x + threadIdx.x;
    if (i < n4) ((float4*)p)[i] = make_float4(0.f, 0.f, 0.f, 0.f);
}
__global__ void k_sentinel(float* __restrict__ out) {
    int i = blockIdx.x * blockDim.x + threadIdx.x;
    if (i < 1024) out[i] = -99999.0f;
}

// ---------------- encoder: encoded = mish(x @ enc_w^T + enc_b), bf16 out ----
__global__ __launch_bounds__(256) void k_encoder(
    const float* __restrict__ x, const float* __restrict__ enc_w,
    const float* __restrict__ enc_b, uint16_t* __restrict__ enc_out) {
    const int tid = threadIdx.x;
    const int lane = tid & 63, wid = tid >> 6;
    const int q = lane >> 4, l15 = lane & 15;
    const int wm = wid >> 1, wj = wid & 1;
    const int j0 = blockIdx.x * 128, b0 = blockIdx.y * 128;

    __shared__ uint16_t a_s[128 * 72];
    __shared__ uint16_t w_s[128 * 72];

#pragma unroll
    for (int jj = 0; jj < 8; ++jj) {
        int u = tid + jj * 256;
        int r = u >> 4, c4 = (u & 15) * 4;
        float4 va = *(const float4*)&x[(size_t)(b0 + r) * 64 + c4];
        float4 vw = *(const float4*)&enc_w[(size_t)(j0 + r) * 64 + c4];
        *(u64*)&a_s[r * 72 + c4] = pack4bf(va);
        *(u64*)&w_s[r * 72 + c4] = pack4bf(vw);
    }
    __syncthreads();

    floatx4 acc[4][4];
#pragma unroll
    for (int mi = 0; mi < 4; ++mi)
#pragma unroll
        for (int nf = 0; nf < 4; ++nf) acc[mi][nf] = (floatx4){0.f, 0.f, 0.f, 0.f};

#pragma unroll
    for (int kc = 0; kc < 2; ++kc) {
        short8 af[4], bfg[4];
#pragma unroll
        for (int mi = 0; mi < 4; ++mi)
            af[mi] = *(const short8*)&a_s[(wm * 64 + mi * 16 + l15) * 72 + kc * 32 + q * 8];
#pragma unroll
        for (int nf = 0; nf < 4; ++nf)
            bfg[nf] = *(const short8*)&w_s[(wj * 64 + nf * 16 + l15) * 72 + kc * 32 + q * 8];
#pragma unroll
        for (int mi = 0; mi < 4; ++mi)
#pragma unroll
            for (int nf = 0; nf < 4; ++nf)
                acc[mi][nf] = __builtin_amdgcn_mfma_f32_16x16x32_bf16(af[mi], bfg[nf], acc[mi][nf], 0, 0, 0);
    }

#pragma unroll
    for (int nf = 0; nf < 4; ++nf) {
        int j = j0 + wj * 64 + nf * 16 + l15;
        float eb = enc_b[j];
#pragma unroll
        for (int mi = 0; mi < 4; ++mi)
#pragma unroll
            for (int r = 0; r < 4; ++r) {
                int b = b0 + wm * 64 + mi * 16 + q * 4 + r;
                float v = acc[mi][nf][r] + eb;
                float sp = (v > 20.f) ? v : log1pf(expf(v));
                float m = v * tanhf(sp);
                enc_out[(size_t)b * 32768 + j] = f2bf(m);
            }
    }
}

// ---------------- shared memory layouts ------------------------------------
struct SGru {
    uint16_t wgi[96 * 520];   // [3g*32r][K(+8 pad)]
    uint16_t wgh[96 * 264];   // [3g*32r][256+8]
    uint16_t h_out[128 * 32]; // publish staging
};
struct SAtt {
    uint16_t hbf[6 * 16 * 264];
    float laP[3][3][16];
    float saT[4][16][17];
    float s_s[16], lg_s[16];
};
union SMem { SGru g; SAtt a; };

// ---------------- pipelined scan kernel ------------------------------------
// grid 224 x 512 thr.
//  b<192: GRU block: sd=b>>5, es=(b&31)>>2 (8 e-slices of 32), bt=b&3.
//  b>=192: attention block ab=b-192 (32 blocks of 16 rows).
// Ring layout: slot[(t&7)] . plane[sd*8+es] (32KB) . row (64B) . col16.
__global__ __launch_bounds__(BTH) void k_scan(
    const uint16_t* __restrict__ enc_bf,
    const uint16_t* __restrict__ wih0_bf, const uint16_t* __restrict__ wihL_bf,
    const uint16_t* __restrict__ whh_bf,
    const float* __restrict__ bih, const float* __restrict__ bhh,
    const uint16_t* __restrict__ law1_bf, const float* __restrict__ la_b1,
    const float* __restrict__ la_w2, const float* __restrict__ la_b2,
    const uint16_t* __restrict__ saw1_bf, const float* __restrict__ sa_b1,
    const float* __restrict__ sa_w2, const float* __restrict__ sa_b2,
    const float* __restrict__ ln_g, const float* __restrict__ ln_b,
    const float* __restrict__ fc_w, const float* __restrict__ fc_b,
    uint16_t* __restrict__ ring, int* produced, int* consumed,
    float* __restrict__ out) {
    const int blk = blockIdx.x;
    const int tid = threadIdx.x;
    const int w = tid >> 6;
    const int lane = tid & 63;
    const int q = lane >> 4, l15 = lane & 15;

    __shared__ SMem sm;

    if (blk < 192) {
        // =================== GRU stage block ===============================
        const int sd = blk >> 5;
        const int l = sd >> 1, dd = sd & 1;
        const int rem = blk & 31;
        const int es = rem >> 2;
        const int bt = rem & 3;
        const int row0 = bt * 128;
        const int Kgi = (l == 0) ? 128 : 512;
        const int ksh = (l == 0) ? 7 : 9;
        const int strgi = Kgi + 8;
        const uint16_t* wih = (l == 0) ? wih0_bf + (size_t)dd * NG * 128
                                       : wihL_bf + (size_t)((l - 1) * 2 + dd) * NG * 512;
        const uint16_t* whhp = whh_bf + (size_t)sd * NG * 256;
        const int ncons = (l < 2) ? 32 : 16;

        // ---- load weights into LDS (once) ----
        for (int flat = tid * 8; flat < 96 * Kgi; flat += BTH * 8) {
            int r = flat >> ksh, c = flat & (Kgi - 1);
            int g = r >> 5, rr = r & 31;
            int srow = g * 256 + es * 32 + rr;
            *(intx4*)&sm.g.wgi[r * strgi + c] = *(const intx4*)&wih[(size_t)srow * Kgi + c];
        }
        for (int flat = tid * 8; flat < 96 * 256; flat += BTH * 8) {
            int r = flat >> 8, c = flat & 255;
            int g = r >> 5, rr = r & 31;
            int srow = g * 256 + es * 32 + rr;
            *(intx4*)&sm.g.wgh[r * 264 + c] = *(const intx4*)&whhp[(size_t)srow * 256 + c];
        }
        float bRs[2], bZs[2], bNs[2], bHNs[2];
        {
            int ba = sd * NG;
#pragma unroll
            for (int sub = 0; sub < 2; ++sub) {
                int e = es * 32 + sub * 16 + l15;
                bRs[sub] = bih[ba + e] + bhh[ba + e];
                bZs[sub] = bih[ba + 256 + e] + bhh[ba + 256 + e];
                bNs[sub] = bih[ba + 512 + e];
                bHNs[sub] = bhh[ba + 512 + e];
            }
        }
        int wofs_gi[2][3], wofs_gh[2][3];
#pragma unroll
        for (int sub = 0; sub < 2; ++sub)
#pragma unroll
            for (int g = 0; g < 3; ++g) {
                wofs_gi[sub][g] = (g * 32 + sub * 16 + l15) * strgi + q * 8;
                wofs_gh[sub][g] = (g * 32 + sub * 16 + l15) * 264 + q * 8;
            }
        float hreg[2][4];
#pragma unroll
        for (int sub = 0; sub < 2; ++sub)
#pragma unroll
            for (int r = 0; r < 4; ++r) hreg[sub][r] = 0.f;

        const int myrow = row0 + w * 16 + l15;
        // loop-invariant per-lane plane offsets (bytes): kc*32KB + row*64 + q*16
        uint32_t vo[8];
#pragma unroll
        for (int kc = 0; kc < 8; ++kc)
            vo[kc] = (uint32_t)(kc * 32768 + myrow * 64 + q * 16);
        const u64 ring_u = (u64)(uintptr_t)ring;
        __syncthreads();

        for (int t = 0; t < NT; ++t) {
            // ---- waits (thread 0): back-pressure, own t-1, upstream t ----
            if (tid == 0) {
                if (t >= R_RING) {
                    const int* cp = &consumed[PIDX(sd, t - R_RING, bt)];
                    while (__hip_atomic_load(cp, __ATOMIC_RELAXED, __HIP_MEMORY_SCOPE_AGENT) < ncons)
                        __builtin_amdgcn_s_sleep(1);
                }
                if (t >= 1) {
                    const int* sp = &produced[PIDX(sd, t - 1, bt)];
                    while (__hip_atomic_load(sp, __ATOMIC_RELAXED, __HIP_MEMORY_SCOPE_AGENT) < 8)
                        __builtin_amdgcn_s_sleep(1);
                }
                if (l > 0) {
                    const int* p0 = &produced[PIDX(2 * (l - 1), t, bt)];
                    const int* p1 = &produced[PIDX(2 * (l - 1) + 1, t, bt)];
                    while (__hip_atomic_load(p0, __ATOMIC_RELAXED, __HIP_MEMORY_SCOPE_AGENT) < 8)
                        __builtin_amdgcn_s_sleep(1);
                    while (__hip_atomic_load(p1, __ATOMIC_RELAXED, __HIP_MEMORY_SCOPE_AGENT) < 8)
                        __builtin_amdgcn_s_sleep(1);
                }
            }
            __syncthreads();

            // ---- A-fragment loads: av[0..7]=gh(t-1), av[8..23]=gi(t) ----
            intx4 av[24];
            const u64 sb_gh = ring_u + (u64)((t - 1) & 7) * (RSLOT * 2) + ((u64)(sd * 8) << 15);
            if (l > 0) {
                const u64 sb0 = ring_u + (u64)(t & 7) * (RSLOT * 2) + ((u64)((2 * l - 2) * 8) << 15);
                if (t > 0)
                    ld_plane8(sb_gh, vo[0], vo[1], vo[2], vo[3], vo[4], vo[5], vo[6], vo[7], av);
                else {
#pragma unroll
                    for (int i = 0; i < 8; ++i) av[i] = (intx4){0, 0, 0, 0};
                }
                ld_plane8(sb0, vo[0], vo[1], vo[2], vo[3], vo[4], vo[5], vo[6], vo[7], av + 8);
                ld_plane8(sb0 + (8u << 15), vo[0], vo[1], vo[2], vo[3], vo[4], vo[5], vo[6], vo[7], av + 16);
                if (t > 0) wait_vm8(av);
                wait_vm8(av + 8);
                wait_vm8(av + 16);
            } else {
                if (t > 0) {
                    ld_plane8(sb_gh, vo[0], vo[1], vo[2], vo[3], vo[4], vo[5], vo[6], vo[7], av);
                } else {
#pragma unroll
                    for (int i = 0; i < 8; ++i) av[i] = (intx4){0, 0, 0, 0};
                }
                const uint16_t* eb = enc_bf + ((size_t)myrow << 15) + t * 128 + q * 8;
#pragma unroll
                for (int kc = 0; kc < 4; ++kc)
                    __builtin_memcpy(&av[8 + kc], eb + kc * 32, 16);
                if (t > 0) wait_vm8(av);
            }

            // ---- MFMA ----
            floatx4 aR[2], aZ[2], aNi[2], aNh[2];
#pragma unroll
            for (int sub = 0; sub < 2; ++sub) {
                floatx4 z = (floatx4){0.f, 0.f, 0.f, 0.f};
                aR[sub] = z; aZ[sub] = z; aNi[sub] = z; aNh[sub] = z;
            }
            const int nkc = Kgi >> 5;
            for (int kc = 0; kc < nkc; ++kc) {
                short8 afr = as_s8(av[8 + kc]);
#pragma unroll
                for (int sub = 0; sub < 2; ++sub) {
                    short8 b0f = *(const short8*)&sm.g.wgi[wofs_gi[sub][0] + kc * 32];
                    short8 b1f = *(const short8*)&sm.g.wgi[wofs_gi[sub][1] + kc * 32];
                    short8 b2f = *(const short8*)&sm.g.wgi[wofs_gi[sub][2] + kc * 32];
                    aR[sub]  = __builtin_amdgcn_mfma_f32_16x16x32_bf16(afr, b0f, aR[sub], 0, 0, 0);
                    aZ[sub]  = __builtin_amdgcn_mfma_f32_16x16x32_bf16(afr, b1f, aZ[sub], 0, 0, 0);
                    aNi[sub] = __builtin_amdgcn_mfma_f32_16x16x32_bf16(afr, b2f, aNi[sub], 0, 0, 0);
                }
            }
#pragma unroll 2
            for (int kc = 0; kc < 8; ++kc) {
                short8 afr = as_s8(av[kc]);
#pragma unroll
                for (int sub = 0; sub < 2; ++sub) {
                    short8 b0f = *(const short8*)&sm.g.wgh[wofs_gh[sub][0] + kc * 32];
                    short8 b1f = *(const short8*)&sm.g.wgh[wofs_gh[sub][1] + kc * 32];
                    short8 b2f = *(const short8*)&sm.g.wgh[wofs_gh[sub][2] + kc * 32];
                    aR[sub]  = __builtin_amdgcn_mfma_f32_16x16x32_bf16(afr, b0f, aR[sub], 0, 0, 0);
                    aZ[sub]  = __builtin_amdgcn_mfma_f32_16x16x32_bf16(afr, b1f, aZ[sub], 0, 0, 0);
                    aNh[sub] = __builtin_amdgcn_mfma_f32_16x16x32_bf16(afr, b2f, aNh[sub], 0, 0, 0);
                }
            }

            // ---- epilogue: gates + state update -> h_out ----
#pragma unroll
            for (int sub = 0; sub < 2; ++sub) {
#pragma unroll
                for (int r = 0; r < 4; ++r) {
                    float rr = sigmoidf_(aR[sub][r] + bRs[sub]);
                    float zz = sigmoidf_(aZ[sub][r] + bZs[sub]);
                    float nn = tanhf(aNi[sub][r] + bNs[sub] + rr * (aNh[sub][r] + bHNs[sub]));
                    float hn = (1.f - zz) * nn + zz * hreg[sub][r];
                    hreg[sub][r] = hn;
                    sm.g.h_out[(w * 16 + q * 4 + r) * 32 + sub * 16 + l15] = f2bf(hn);
                }
            }
            __syncthreads();
            // ---- publish slice: contiguous 8KB burst per block ----
            {
                int r = tid >> 2, part = tid & 3;
                uint16_t* dst = ring + (size_t)(t & 7) * RSLOT
                              + ((size_t)(sd * 8 + es) << 14)
                              + (size_t)(row0 + r) * 32 + part * 8;
                st_coh16_wait(dst, *(const intx4*)&sm.g.h_out[r * 32 + part * 8]);
            }
            __syncthreads();   // every thread drained its own store above
            if (tid == 0) {
                __hip_atomic_fetch_add(&produced[PIDX(sd, t, bt)], 1,
                                       __ATOMIC_RELAXED, __HIP_MEMORY_SCOPE_AGENT);
                if (l > 0) {
                    __hip_atomic_fetch_add(&consumed[PIDX(2 * l - 2, t, bt)], 1,
                                           __ATOMIC_RELAXED, __HIP_MEMORY_SCOPE_AGENT);
                    __hip_atomic_fetch_add(&consumed[PIDX(2 * l - 1, t, bt)], 1,
                                           __ATOMIC_RELAXED, __HIP_MEMORY_SCOPE_AGENT);
                }
                if (t >= 1)
                    __hip_atomic_fetch_add(&consumed[PIDX(sd, t - 1, bt)], 1,
                                           __ATOMIC_RELAXED, __HIP_MEMORY_SCOPE_AGENT);
            }
        }
        return;
    }

    // =================== attention block (16 rows) =========================
    const int ab = blk - 192;
    const int b0 = ab * 16;
    const int bt = ab >> 3;
    const int lA = w / 3, nfA = w % 3;
    const float b1A = la_b1[lA * 48 + nfA * 16 + l15];
    const float w2A = la_w2[lA * 48 + nfA * 16 + l15];
    float b1B = 0.f, w2B = 0.f;
    if (w == 0) { b1B = la_b1[2 * 48 + 2 * 16 + l15]; w2B = la_w2[2 * 48 + 2 * 16 + l15]; }
    float nacc[16];
#pragma unroll
    for (int j = 0; j < 16; ++j) nacc[j] = 0.f;
    float m_r = -1e30f, d_r = 0.f;

    for (int t = 0; t < NT; ++t) {
        if (tid == 0) {
            const int* p4 = &produced[PIDX(4, t, bt)];
            const int* p5 = &produced[PIDX(5, t, bt)];
            while (__hip_atomic_load(p4, __ATOMIC_RELAXED, __HIP_MEMORY_SCOPE_AGENT) < 8)
                __builtin_amdgcn_s_sleep(1);
            while (__hip_atomic_load(p5, __ATOMIC_RELAXED, __HIP_MEMORY_SCOPE_AGENT) < 8)
                __builtin_amdgcn_s_sleep(1);
        }
        __syncthreads();
        // ---- stage all 6 states into hbf ----
        {
            const uint16_t* base = ring + (size_t)(t & 7) * RSLOT;
            const uint16_t* ps[6];
            int di[6];
#pragma unroll
            for (int i = 0; i < 6; ++i) {
                int f = i * 512 + tid;
                int s = f >> 9, r = (f >> 5) & 15, g = f & 31;
                int esx = g >> 2, c16 = g & 3;
                ps[i] = base + ((size_t)(s * 8 + esx) << 14) + (size_t)(b0 + r) * 32 + c16 * 8;
                di[i] = (s * 16 + r) * 264 + g * 8;
            }
            intx4 v[6];
            ld_sc6(ps[0], ps[1], ps[2], ps[3], ps[4], ps[5], v);
#pragma unroll
            for (int i = 0; i < 6; ++i) *(intx4*)&sm.a.hbf[di[i]] = v[i];
        }
        __syncthreads();
        if (tid == 0) {
#pragma unroll
            for (int s = 0; s < 6; ++s)
                __hip_atomic_fetch_add(&consumed[PIDX(s, t, bt)], 1,
                                       __ATOMIC_RELAXED, __HIP_MEMORY_SCOPE_AGENT);
        }
        // ---- job A: la(lA, nfA) ----
        {
            floatx4 ac = (floatx4){0.f, 0.f, 0.f, 0.f};
#pragma unroll 2
            for (int kc = 0; kc < 512; kc += 32) {
                int k = kc + q * 8;
                int s = 2 * lA + (k >= 256 ? 1 : 0);
                short8 afr = *(const short8*)&sm.a.hbf[(s * 16 + l15) * 264 + (k & 255)];
                const uint16_t* wr = law1_bf + (size_t)(lA * 48 + nfA * 16 + l15) * 512 + k;
                ac = __builtin_amdgcn_mfma_f32_16x16x32_bf16(afr, *(const short8*)wr, ac, 0, 0, 0);
            }
#pragma unroll
            for (int r = 0; r < 4; ++r) {
                float v = geluf_(ac[r] + b1A) * w2A;
                v += __shfl_xor(v, 1, 64);
                v += __shfl_xor(v, 2, 64);
                v += __shfl_xor(v, 4, 64);
                v += __shfl_xor(v, 8, 64);
                if (l15 == 0) sm.a.laP[lA][nfA][q * 4 + r] = v;
            }
        }
        // ---- job B ----
        if (w == 0) {           // la(2,2)
            floatx4 ac = (floatx4){0.f, 0.f, 0.f, 0.f};
#pragma unroll 2
            for (int kc = 0; kc < 512; kc += 32) {
                int k = kc + q * 8;
                int s = 4 + (k >= 256 ? 1 : 0);
                short8 afr = *(const short8*)&sm.a.hbf[(s * 16 + l15) * 264 + (k & 255)];
                const uint16_t* wr = law1_bf + (size_t)(2 * 48 + 2 * 16 + l15) * 512 + k;
                ac = __builtin_amdgcn_mfma_f32_16x16x32_bf16(afr, *(const short8*)wr, ac, 0, 0, 0);
            }
#pragma unroll
            for (int r = 0; r < 4; ++r) {
                float v = geluf_(ac[r] + b1B) * w2B;
                v += __shfl_xor(v, 1, 64);
                v += __shfl_xor(v, 2, 64);
                v += __shfl_xor(v, 4, 64);
                v += __shfl_xor(v, 8, 64);
                if (l15 == 0) sm.a.laP[2][2][q * 4 + r] = v;
            }
        } else if (w <= 4) {    // sa tile nf = w-1 (raw pre-acts)
            int nf = w - 1;
            floatx4 ac = (floatx4){0.f, 0.f, 0.f, 0.f};
#pragma unroll 2
            for (int kc = 0; kc < 512; kc += 32) {
                int k = kc + q * 8;
                int s = 4 + (k >= 256 ? 1 : 0);
                short8 afr = *(const short8*)&sm.a.hbf[(s * 16 + l15) * 264 + (k & 255)];
                const uint16_t* wr = saw1_bf + (size_t)(nf * 16 + l15) * 512 + k;
                ac = __builtin_amdgcn_mfma_f32_16x16x32_bf16(afr, *(const short8*)wr, ac, 0, 0, 0);
            }
#pragma unroll
            for (int r = 0; r < 4; ++r) sm.a.saT[nf][q * 4 + r][l15] = ac[r];
        }
        __syncthreads();
        // ---- combine: s and logit per row (wave 0) ----
        if (w == 0) {
            int row = l15;
            float sv = 0.f;
#pragma unroll
            for (int l = 0; l < 3; ++l)
                sv += sigmoidf_(sm.a.laP[l][0][row] + sm.a.laP[l][1][row] +
                                sm.a.laP[l][2][row] + la_b2[l]);
            float a2 = 0.f;
#pragma unroll
            for (int i = 0; i < 16; ++i) {
                int c = q * 16 + i;
                float pre = sv * sm.a.saT[q][row][i] + sa_b1[c];
                a2 += pre * sigmoidf_(pre) * sa_w2[c];
            }
            a2 += __shfl_xor(a2, 16, 64);
            a2 += __shfl_xor(a2, 32, 64);
            if (q == 0 && lane < 16) { sm.a.s_s[row] = sv; sm.a.lg_s[row] = a2 + sa_b2[0]; }
        }
        __syncthreads();
        // ---- online softmax update (wave w owns rows 2w, 2w+1) ----
        {
            int myrow = 2 * w + (lane >> 5);
            int ci = lane & 31;
            float lg = sm.a.lg_s[myrow], sv = sm.a.s_s[myrow];
            float mn = fmaxf(m_r, lg);
            float cs = expf(m_r - mn);
            float e = expf(lg - mn);
            m_r = mn;
            d_r = d_r * cs + e;
            float wf = e * sv;
            int st = 4 + (ci >> 4);
            int c0 = (ci & 15) * 16;
            const uint16_t* hp = &sm.a.hbf[(size_t)(st * 16 + myrow) * 264 + c0];
            short8 o0 = *(const short8*)hp;
            short8 o1 = *(const short8*)(hp + 8);
#pragma unroll
            for (int j = 0; j < 8; ++j) {
                nacc[j]     = nacc[j] * cs + wf * bf2f((uint16_t)o0[j]);
                nacc[8 + j] = nacc[8 + j] * cs + wf * bf2f((uint16_t)o1[j]);
            }
        }
        __syncthreads();   // protect hbf/s_s before next step's staging
    }

    // ---- finalize: context -> LN -> FC ----
    {
        int myrow = 2 * w + (lane >> 5);
        int ci = lane & 31;
        float dinv = 1.f / d_r;
        float cv[16];
        float s1 = 0.f, s2 = 0.f;
#pragma unroll
        for (int j = 0; j < 16; ++j) {
            cv[j] = nacc[j] * dinv;
            s1 += cv[j];
            s2 += cv[j] * cv[j];
        }
        s1 += __shfl_xor(s1, 1, 64);  s2 += __shfl_xor(s2, 1, 64);
        s1 += __shfl_xor(s1, 2, 64);  s2 += __shfl_xor(s2, 2, 64);
        s1 += __shfl_xor(s1, 4, 64);  s2 += __shfl_xor(s2, 4, 64);
        s1 += __shfl_xor(s1, 8, 64);  s2 += __shfl_xor(s2, 8, 64);
        s1 += __shfl_xor(s1, 16, 64); s2 += __shfl_xor(s2, 16, 64);
        float mean = s1 / 512.f;
        float var = s2 / 512.f - mean * mean;
        float rstd = rsqrtf(var + 1e-5f);
        float p0 = 0.f, p1 = 0.f;
#pragma unroll
        for (int j = 0; j < 16; ++j) {
            int g = ci * 16 + j;
            float nv = (cv[j] - mean) * rstd * ln_g[g] + ln_b[g];
            p0 += nv * fc_w[g];
            p1 += nv * fc_w[512 + g];
        }
        p0 += __shfl_xor(p0, 1, 64);  p1 += __shfl_xor(p1, 1, 64);
        p0 += __shfl_xor(p0, 2, 64);  p1 += __shfl_xor(p1, 2, 64);
        p0 += __shfl_xor(p0, 4, 64);  p1 += __shfl_xor(p1, 4, 64);
        p0 += __shfl_xor(p0, 8, 64);  p1 += __shfl_xor(p1, 8, 64);
        p0 += __shfl_xor(p0, 16, 64); p1 += __shfl_xor(p1, 16, 64);
        if ((lane & 31) == 0) {
            out[(b0 + myrow) * 2 + 0] = p0 + fc_b[0];
            out[(b0 + myrow) * 2 + 1] = p1 + fc_b[1];
        }
    }
}

// ---------------------------------------------------------------------------
extern "C" void kernel_launch(void* const* d_in, const int* in_sizes, int n_in,
                              void* d_out, int out_size, void* d_ws, size_t ws_size,
                              hipStream_t stream) {
    const float* x     = (const float*)d_in[0];
    const float* enc_w = (const float*)d_in[1];
    const float* enc_b = (const float*)d_in[2];
    const float* wih0  = (const float*)d_in[3];
    const float* wihL  = (const float*)d_in[4];
    const float* whh   = (const float*)d_in[5];
    const float* bih   = (const float*)d_in[6];
    const float* bhh   = (const float*)d_in[7];
    const float* la_w1 = (const float*)d_in[8];
    const float* la_b1 = (const float*)d_in[9];
    const float* la_w2 = (const float*)d_in[10];
    const float* la_b2 = (const float*)d_in[11];
    const float* sa_w1 = (const float*)d_in[12];
    const float* sa_b1 = (const float*)d_in[13];
    const float* sa_w2 = (const float*)d_in[14];
    const float* sa_b2 = (const float*)d_in[15];
    const float* ln_g  = (const float*)d_in[16];
    const float* ln_b  = (const float*)d_in[17];
    const float* fc_w  = (const float*)d_in[18];
    const float* fc_b  = (const float*)d_in[19];
    float* out = (float*)d_out;

    uint8_t* wsb = (uint8_t*)d_ws;
    size_t off = 0;
    auto alloc = [&](size_t bytes) -> void* {
        void* p = wsb + off;
        off += (bytes + 255) & ~(size_t)255;
        return p;
    };
    uint16_t* enc_bf  = (uint16_t*)alloc((size_t)NB * 32768 * 2);          // 33.55 MB
    uint16_t* wih0_bf = (uint16_t*)alloc((size_t)2 * NG * 128 * 2);        // 0.39 MB
    uint16_t* wihL_bf = (uint16_t*)alloc((size_t)2 * 2 * NG * 512 * 2);    // 3.15 MB
    uint16_t* whh_bf  = (uint16_t*)alloc((size_t)3 * 2 * NG * 256 * 2);    // 2.36 MB
    uint16_t* law1_bf = (uint16_t*)alloc((size_t)3 * 48 * 512 * 2);        // 0.15 MB
    uint16_t* saw1_bf = (uint16_t*)alloc((size_t)64 * 512 * 2);            // 0.07 MB
    uint16_t* ring    = (uint16_t*)alloc((size_t)R_RING * RSLOT * 2);      // 12.58 MB
    int*      produced= (int*)alloc((size_t)6 * NT * 4 * 4);               // 24 KB
    int*      consumed= (int*)alloc((size_t)6 * NT * 4 * 4);               // 24 KB
    // total ~52.3 MB

    if (ws_size < off) {
        k_sentinel<<<4, 256, 0, stream>>>(out);
        return;
    }

    auto cvt = [&](const float* s, uint16_t* dmem, int n) {
        int n4 = n / 4;
        k_cvt<<<(n4 + 255) / 256, 256, 0, stream>>>(s, dmem, n4);
    };
    cvt(wih0, wih0_bf, 196608);
    cvt(wihL, wihL_bf, 1572864);
    cvt(whh, whh_bf, 1179648);
    cvt(la_w1, law1_bf, 73728);
    cvt(sa_w1, saw1_bf, 32768);
    // zero produced+consumed (contiguous: 2 * 6144 ints = 3072 float4)
    k_zero<<<12, 256, 0, stream>>>((float*)produced, 3072);

    k_encoder<<<dim3(256, 4), 256, 0, stream>>>(x, enc_w, enc_b, enc_bf);

    k_scan<<<224, BTH, 0, stream>>>(enc_bf, wih0_bf, wihL_bf, whh_bf,
                                    bih, bhh, law1_bf, la_b1, la_w2, la_b2,
                                    saw1_bf, sa_b1, sa_w2, sa_b2,
                                    ln_g, ln_b, fc_w, fc_b,
                                    ring, produced, consumed, out);
}